// Round 9
// baseline (417.807 us; speedup 1.0000x reference)
//
#include <hip/hip_runtime.h>
#include <math.h>

#define BATCH 8
#define SEQ   2048
#define DM    256
#define DQK   128
#define NHEADS 8
#define NK    16
#define DFF   1024

typedef __attribute__((ext_vector_type(8))) short short8;
typedef __attribute__((ext_vector_type(8))) _Float16 half8;
typedef __attribute__((ext_vector_type(4))) float floatx4;
typedef unsigned long long ull;

__device__ __forceinline__ unsigned short f2bf(float f) {
    unsigned int u = __float_as_uint(f);
    u += 0x7fffu + ((u >> 16) & 1u);          // round-to-nearest-even
    return (unsigned short)(u >> 16);
}

__device__ __forceinline__ float gelu_fast(float h) {
    float y = 0.7978845608028654f * (h + 0.044715f * h * h * h);
    float e = __expf(2.f * y);
    float t = 1.f - 2.f / (e + 1.f);
    return 0.5f * h * (1.f + t);
}

// composite sort key: primary score desc, secondary idx asc. Unique per idx.
__device__ __forceinline__ ull mkkey(float f, int gidx) {
    unsigned int u = __float_as_uint(f);
    u ^= (unsigned int)((int)u >> 31) | 0x80000000u;   // sortable float
    return ((ull)u << 32) | (unsigned int)(2047 - gidx);
}

__device__ __forceinline__ ull shfl_xor_u64(ull v, int m) {
    unsigned int lo = (unsigned int)v, hi = (unsigned int)(v >> 32);
    lo = __shfl_xor(lo, m);
    hi = __shfl_xor(hi, m);
    return ((ull)hi << 32) | lo;
}

// ---------------------------------------------------------------------------
// Kernel W: repack W1/W2/Wv/Wo fp32 -> bf16 MFMA B-fragment order, PLUS
// transpose Wq/Wk (256x128 -> 128x256 fp32) so proj_qk can float4-load
// its weight stream. Transposes land in the vall slot (dead until proj_v).
// ---------------------------------------------------------------------------
__global__ __launch_bounds__(256) void conv_kernel(
    const float* __restrict__ W1, const float* __restrict__ W2,
    const float* __restrict__ Wv, const float* __restrict__ Wo,
    const float* __restrict__ Wq, const float* __restrict__ Wk,
    unsigned short* __restrict__ W1f, unsigned short* __restrict__ W2f,
    unsigned short* __restrict__ Wvf, unsigned short* __restrict__ Wof,
    float* __restrict__ WqT, float* __restrict__ WkT)
{
    int g = blockIdx.x * 256 + threadIdx.x;
    if (g >= 81920) {                 // transpose path
        int e2 = g - 81920;
        const float* Wsrc = (e2 < 32768) ? Wq : Wk;
        float* Wdst       = (e2 < 32768) ? WqT : WkT;
        e2 &= 32767;
        int c = e2 >> 8, d = e2 & 255;          // Wdst[c][d] = Wsrc[d][c]
        Wdst[e2] = Wsrc[(size_t)d * DQK + c];
        return;
    }
    const float* W; unsigned short* O; int e, stride;
    if (g < 32768)      { W = W1; O = W1f; e = g;         stride = DFF; }
    else if (g < 65536) { W = W2; O = W2f; e = g - 32768; stride = DM;  }
    else if (g < 73728) { W = Wv; O = Wvf; e = g - 65536; stride = DM;  }
    else                { W = Wo; O = Wof; e = g - 73728; stride = DM;  }
    int lane = e & 63;
    int kk, nt;
    if (g < 32768)      { kk = (e >> 6) & 7;  nt = e >> 9;  }
    else if (g < 65536) { kk = (e >> 6) & 31; nt = e >> 11; }
    else                { kk = (e >> 6) & 7;  nt = e >> 9;  }
    int n = nt * 16 + (lane & 15);
    int k0 = kk * 32 + (lane >> 4) * 8;
    unsigned int pk[4];
    #pragma unroll
    for (int jj = 0; jj < 4; ++jj) {
        unsigned short lo = f2bf(W[(size_t)(k0 + 2 * jj) * stride + n]);
        unsigned short hi = f2bf(W[(size_t)(k0 + 2 * jj + 1) * stride + n]);
        pk[jj] = (unsigned int)lo | ((unsigned int)hi << 16);
    }
    *(uint4*)(O + (size_t)e * 8) = make_uint4(pk[0], pk[1], pk[2], pk[3]);
}

// ---------------------------------------------------------------------------
// Kernel A1: q/k projections — 8 tokens/block. Weight stream now reads the
// TRANSPOSED WqT/WkT with float4 loads (512 -> 128 load instrs/thread).
// fmaf accumulation order (d ascending, per token) is BIT-IDENTICAL to the
// passing chain; reductions/normalize unchanged -> identical qn/kn bits.
// ---------------------------------------------------------------------------
__global__ __launch_bounds__(256) void proj_qk_kernel(
    const float* __restrict__ x,
    const float* __restrict__ WqT, const float* __restrict__ bq,
    const float* __restrict__ WkT, const float* __restrict__ bk,
    float* __restrict__ qn, float* __restrict__ kn,
    unsigned short* __restrict__ knTh, unsigned short* __restrict__ knTl,
    float* __restrict__ knsq)
{
    __shared__ __align__(16) float ks[8 * 128];
    __shared__ float nred[8][2], kred[8][2], k2red[8][2];

    const int tid = threadIdx.x;
    const int b = blockIdx.x & 7;
    const int chunk = blockIdx.x >> 3;
    const size_t t0 = (size_t)b * SEQ + (size_t)chunk * 8;

    {
        const int col = tid & 127, half = tid >> 7;
        // wave-uniform row bases (half is constant within a wave)
        const int half_u = __builtin_amdgcn_readfirstlane(half);
        const float* xrow[4];
        #pragma unroll
        for (int t = 0; t < 4; ++t)
            xrow[t] = x + (t0 + (size_t)(half_u * 4 + t)) * DM;
        const float* wqp = WqT + (size_t)col * 256;
        const float* wkp = WkT + (size_t)col * 256;

        float qa[4] = {0.f, 0.f, 0.f, 0.f}, ka[4] = {0.f, 0.f, 0.f, 0.f};
        for (int d = 0; d < 256; d += 4) {
            float4 xv[4];
            #pragma unroll
            for (int t = 0; t < 4; ++t) xv[t] = *(const float4*)(xrow[t] + d);
            float4 wq4 = *(const float4*)(wqp + d);
            float4 wk4 = *(const float4*)(wkp + d);
            #pragma unroll
            for (int dd = 0; dd < 4; ++dd) {
                float wq = (dd == 0) ? wq4.x : (dd == 1) ? wq4.y
                         : (dd == 2) ? wq4.z : wq4.w;
                float wk = (dd == 0) ? wk4.x : (dd == 1) ? wk4.y
                         : (dd == 2) ? wk4.z : wk4.w;
                #pragma unroll
                for (int t = 0; t < 4; ++t) {
                    float xval = (dd == 0) ? xv[t].x : (dd == 1) ? xv[t].y
                               : (dd == 2) ? xv[t].z : xv[t].w;
                    qa[t] = fmaf(xval, wq, qa[t]);
                    ka[t] = fmaf(xval, wk, ka[t]);
                }
            }
        }
        #pragma unroll
        for (int t = 0; t < 4; ++t) { qa[t] += bq[col]; ka[t] += bk[col]; }

        const int sub = (tid >> 6) & 1;
        #pragma unroll
        for (int t = 0; t < 4; ++t) {
            float sq = qa[t] * qa[t], sk = ka[t] * ka[t];
            #pragma unroll
            for (int m = 1; m < 64; m <<= 1) { sq += __shfl_xor(sq, m); sk += __shfl_xor(sk, m); }
            if ((tid & 63) == 0) { nred[half * 4 + t][sub] = sq; kred[half * 4 + t][sub] = sk; }
        }
        __syncthreads();
        float kvv[4];
        #pragma unroll
        for (int t = 0; t < 4; ++t) {
            int tok = half * 4 + t;
            float nq = sqrtf(nred[tok][0] + nred[tok][1]);
            float nk = sqrtf(kred[tok][0] + kred[tok][1]);
            float qv = qa[t] / fmaxf(nq, 1e-12f);
            float kv = ka[t] / fmaxf(nk, 1e-12f);
            qn[(t0 + tok) * DQK + col] = qv;
            kn[(t0 + tok) * DQK + col] = kv;
            ks[tok * 128 + col] = kv;
            kvv[t] = kv;
        }
        #pragma unroll
        for (int t = 0; t < 4; ++t) {
            float s2 = kvv[t] * kvv[t];
            #pragma unroll
            for (int m = 1; m < 64; m <<= 1) s2 += __shfl_xor(s2, m);
            if ((tid & 63) == 0) k2red[half * 4 + t][sub] = s2;
        }
        __syncthreads();
        if (tid < 8) knsq[t0 + tid] = k2red[tid][0] + k2red[tid][1];
    }

    // --- K^T -> fp16 hi/lo B-fragments ---
    {
        const int e   = tid & 127;
        const int sel = tid >> 7;           // 0 = hi, 1 = lo(*4096)
        const int key = e & 7;
        const int kq  = e >> 3;             // kk*4 + qd
        const int kk  = kq >> 2, qd = kq & 3;
        const int nt  = chunk >> 1;
        const int n   = ((chunk & 1) << 3) + key;
        const float* src = &ks[key * 128 + kk * 32 + qd * 8];
        unsigned int pk[4];
        #pragma unroll
        for (int jj = 0; jj < 4; ++jj) {
            float v0 = src[2 * jj], v1 = src[2 * jj + 1];
            _Float16 h0 = (_Float16)v0, h1 = (_Float16)v1;
            unsigned short u0, u1;
            if (sel == 0) {
                u0 = __builtin_bit_cast(unsigned short, h0);
                u1 = __builtin_bit_cast(unsigned short, h1);
            } else {
                _Float16 l0 = (_Float16)((v0 - (float)h0) * 4096.f);
                _Float16 l1 = (_Float16)((v1 - (float)h1) * 4096.f);
                u0 = __builtin_bit_cast(unsigned short, l0);
                u1 = __builtin_bit_cast(unsigned short, l1);
            }
            pk[jj] = (unsigned int)u0 | ((unsigned int)u1 << 16);
        }
        unsigned short* dst = (sel ? knTl : knTh)
            + (size_t)b * 262144
            + (size_t)((nt * 4 + kk) * 64 + qd * 16 + n) * 8;
        *(uint4*)dst = make_uint4(pk[0], pk[1], pk[2], pk[3]);
    }
}

// ---------------------------------------------------------------------------
// Kernel A2: v projection via bf16 MFMA (unchanged — passing).
// ---------------------------------------------------------------------------
__global__ __launch_bounds__(256) void proj_v_kernel(
    const float* __restrict__ x,
    const float* __restrict__ bv, const float* __restrict__ g1,
    const float* __restrict__ b1,
    const unsigned short* __restrict__ Wvf, float* __restrict__ vall)
{
    __shared__ __align__(16) float xs[16][260];
    __shared__ float stat_m[16], stat_r[16];
    __shared__ float bvs[256], g1s[256], b1s[256];

    const int tid = threadIdx.x;
    const int lane = tid & 63, wave = tid >> 6;
    const int quad = lane >> 4, lr = lane & 15;
    const size_t t0 = (size_t)blockIdx.x * 16;

    for (int i = tid; i < 16 * 256; i += 256) xs[i >> 8][i & 255] = x[t0 * DM + i];
    bvs[tid] = bv[tid]; g1s[tid] = g1[tid]; b1s[tid] = b1[tid];
    __syncthreads();

    {
        int tok = tid >> 4, l = tid & 15;
        float s = 0.f, s2 = 0.f;
        #pragma unroll
        for (int i = 0; i < 16; ++i) {
            float v = xs[tok][l + 16 * i];
            s += v; s2 += v * v;
        }
        #pragma unroll
        for (int m = 1; m < 16; m <<= 1) { s += __shfl_xor(s, m); s2 += __shfl_xor(s2, m); }
        if (l == 0) {
            float mean = s * (1.f / 256.f);
            float var  = s2 * (1.f / 256.f) - mean * mean;
            stat_m[tok] = mean;
            stat_r[tok] = rsqrtf(var + 1e-5f);
        }
    }
    __syncthreads();

    short8 av[8];
    {
        float mm = stat_m[lr], rr = stat_r[lr];
        #pragma unroll
        for (int kk = 0; kk < 8; ++kk) {
            #pragma unroll
            for (int j = 0; j < 8; ++j) {
                int k = kk * 32 + quad * 8 + j;
                float v = (xs[lr][k] - mm) * rr * g1s[k] + b1s[k];
                av[kk][j] = (short)f2bf(v);
            }
        }
    }
    floatx4 acc[4];
    #pragma unroll
    for (int nt = 0; nt < 4; ++nt) acc[nt] = (floatx4){0.f, 0.f, 0.f, 0.f};
    #pragma unroll
    for (int nt = 0; nt < 4; ++nt) {
        #pragma unroll
        for (int kk = 0; kk < 8; ++kk) {
            short8 bfr = *(const short8*)(Wvf + ((size_t)(((wave * 4 + nt) * 8 + kk) * 64) + lane) * 8);
            acc[nt] = __builtin_amdgcn_mfma_f32_16x16x32_bf16(av[kk], bfr, acc[nt], 0, 0, 0);
        }
    }
    #pragma unroll
    for (int nt = 0; nt < 4; ++nt) {
        int col = (wave * 4 + nt) * 16 + lr;
        float bb = bvs[col];
        #pragma unroll
        for (int reg = 0; reg < 4; ++reg) {
            int row = quad * 4 + reg;
            vall[(t0 + row) * DM + col] = acc[nt][reg] + bb;
        }
    }
}

// ---------------------------------------------------------------------------
// Kernel B: attn — VERBATIM R7/R8 (passing, ~161us).
// ---------------------------------------------------------------------------
__global__ __launch_bounds__(256, 4) void attn_kernel(
    const float* __restrict__ x,
    const float* __restrict__ qn_g, const float* __restrict__ kn_g,
    const unsigned short* __restrict__ knTh, const unsigned short* __restrict__ knTl,
    const float* __restrict__ knsq_g,
    const float* __restrict__ vall,
    const unsigned short* __restrict__ Wof, const float* __restrict__ bo,
    const float* __restrict__ rw, float* __restrict__ out)
{
    __shared__ __align__(16) float s_ld[16 * 512];      // exactly 32KB
    float* attn_s = s_ld;            // 16*128 floats
    float* o8     = s_ld + 2048;     // 16*260 floats (stride 260: conflict-free)

    const int tid = threadIdx.x;
    const int lane = tid & 63, wave = tid >> 6;
    const int quad = lane >> 4, lr = lane & 15;
    const int sg = lane >> 5, sl = lane & 31;     // 32-lane subgroup
    const int sgid = wave * 2 + sg;               // 0..7
    const int b = blockIdx.x & 7;
    const int chunk = blockIdx.x >> 3;            // 0..127
    const size_t tq0 = (size_t)b * SEQ + (size_t)chunk * 16;
    const size_t rowb = (size_t)b * SEQ;

    half8 a_hi[4], a_lo[4];
    {
        const float* qrow = qn_g + (tq0 + lr) * DQK + quad * 8;
        #pragma unroll
        for (int kk = 0; kk < 4; ++kk) {
            float4 fa = *(const float4*)(qrow + kk * 32);
            float4 fb = *(const float4*)(qrow + kk * 32 + 4);
            float vv[8] = {fa.x, fa.y, fa.z, fa.w, fb.x, fb.y, fb.z, fb.w};
            #pragma unroll
            for (int j = 0; j < 8; ++j) {
                float v = vv[j];
                _Float16 h = (_Float16)v;
                a_hi[kk][j] = h;
                a_lo[kk][j] = (_Float16)((v - (float)h) * 4096.f);
            }
        }
    }

    const unsigned short* bh = knTh + (size_t)b * 262144;
    const unsigned short* bl = knTl + (size_t)b * 262144;
    const float* ksqb = knsq_g + rowb;

    ull c0[2], c1[2];          // candidate regs: lane sl holds ranks sl, sl+32

    for (int q4 = 0; q4 < 4; ++q4) {
        if (q4) __syncthreads();

        for (int t = 0; t < 8; ++t) {
            const int tile = q4 * 32 + wave * 8 + t;
            const unsigned short* ph = bh + (size_t)tile * 2048 + lane * 8;
            const unsigned short* pl = bl + (size_t)tile * 2048 + lane * 8;
            floatx4 am  = (floatx4){0.f, 0.f, 0.f, 0.f};
            floatx4 ax1 = (floatx4){0.f, 0.f, 0.f, 0.f};
            floatx4 ax2 = (floatx4){0.f, 0.f, 0.f, 0.f};
            #pragma unroll
            for (int kk = 0; kk < 4; ++kk) {
                half8 bhf = *(const half8*)(ph + kk * 512);
                half8 blf = *(const half8*)(pl + kk * 512);
                am  = __builtin_amdgcn_mfma_f32_16x16x32_f16(a_hi[kk], bhf, am,  0, 0, 0);
                ax1 = __builtin_amdgcn_mfma_f32_16x16x32_f16(a_hi[kk], blf, ax1, 0, 0, 0);
                ax2 = __builtin_amdgcn_mfma_f32_16x16x32_f16(a_lo[kk], bhf, ax2, 0, 0, 0);
            }
            const int keyloc = (wave * 8 + t) * 16 + lr;
            const float kq = ksqb[q4 * 512 + keyloc];
            #pragma unroll
            for (int r = 0; r < 4; ++r) {
                s_ld[(quad * 4 + r) * 512 + keyloc] =
                    2.f * (am[r] + (ax1[r] + ax2[r]) * (1.f / 4096.f)) - kq;
            }
        }
        __syncthreads();

        #pragma unroll
        for (int qi = 0; qi < 2; ++qi) {
            const int q = sgid + 8 * qi;
            const float* srow = &s_ld[q * 512 + sl];
            float f0 = -INFINITY, f1 = -INFINITY;
            int   i0 = 0, i1 = 0;
            #pragma unroll
            for (int i = 0; i < 16; ++i) {
                float f = srow[32 * i];
                int gidx = q4 * 512 + sl + 32 * i;
                bool a  = f > f0;
                bool bb = f > f1;
                f1 = a ? f0 : (bb ? f    : f1);
                i1 = a ? i0 : (bb ? gidx : i1);
                f0 = a ? f    : f0;
                i0 = a ? gidx : i0;
            }
            ull k2v = mkkey(f1, i1);
            ull cur = mkkey(f0, i0);
            int cnt = 0;
            for (int r = 0; r < NK; ++r) {
                ull w = cur;
                #pragma unroll
                for (int m = 1; m < 32; m <<= 1) {
                    ull o = shfl_xor_u64(w, m);
                    if (o > w) w = o;
                }
                const int slot = q4 * 16 + r;
                if (sl == slot)      c0[qi] = w;
                if (sl == slot - 32) c1[qi] = w;
                if (cur == w) {
                    ++cnt;
                    if (cnt == 1) cur = k2v;
                    else {
                        ull best = 0;
                        #pragma unroll
                        for (int i = 0; i < 16; ++i) {
                            float f = srow[32 * i];
                            ull k = mkkey(f, q4 * 512 + sl + 32 * i);
                            if (k < w && k > best) best = k;
                        }
                        cur = best;
                    }
                }
            }
        }
    }
    __syncthreads();

    int tidx[2] = {0, 0};
    #pragma unroll
    for (int qi = 0; qi < 2; ++qi) {
        ull ca = c0[qi], cb = c1[qi];
        ull hi = ca > cb ? ca : cb;
        ull lo = ca > cb ? cb : ca;
        ull cur = hi;
        int cnt = 0;
        for (int r = 0; r < NK; ++r) {
            ull w = cur;
            #pragma unroll
            for (int m = 1; m < 32; m <<= 1) {
                ull o = shfl_xor_u64(w, m);
                if (o > w) w = o;
            }
            if (sl == r) tidx[qi] = 2047 - (int)(unsigned int)(w & 0xFFFFFFFFull);
            if (cur == w) { ++cnt; cur = (cnt == 1) ? lo : 0ull; }
        }
    }

    #pragma unroll
    for (int qq = 0; qq < 4; ++qq) {
        const int sgq = qq & 1;
        const int qiq = qq >> 1;
        const int q   = wave * 2 + sgq + 8 * qiq;
        const int srcb = sgq * 32;
        const int h = lane >> 3;
        const int k1 = lane & 7, k2 = 8 + (lane & 7);
        const int i1 = __shfl(tidx[qiq], srcb + k1);
        const int i2 = __shfl(tidx[qiq], srcb + k2);
        const float* qrow = qn_g + (tq0 + q) * DQK + h * 16;
        const float* kr1 = kn_g + (rowb + i1) * DQK + h * 16;
        const float* kr2 = kn_g + (rowb + i2) * DQK + h * 16;
        float lg1 = 0.f, lg2 = 0.f;
        #pragma unroll
        for (int d = 0; d < 16; d += 4) {
            float4 qv = *(const float4*)&qrow[d];
            float4 a1 = *(const float4*)&kr1[d];
            float4 a2 = *(const float4*)&kr2[d];
            lg1 = fmaf(qv.x, a1.x, lg1); lg1 = fmaf(qv.y, a1.y, lg1);
            lg1 = fmaf(qv.z, a1.z, lg1); lg1 = fmaf(qv.w, a1.w, lg1);
            lg2 = fmaf(qv.x, a2.x, lg2); lg2 = fmaf(qv.y, a2.y, lg2);
            lg2 = fmaf(qv.z, a2.z, lg2); lg2 = fmaf(qv.w, a2.w, lg2);
        }
        lg1 *= 0.25f; lg2 *= 0.25f;
        float mx = fmaxf(lg1, lg2);
        #pragma unroll
        for (int m = 1; m < 8; m <<= 1) mx = fmaxf(mx, __shfl_xor(mx, m));
        float e1 = expf(lg1 - mx), e2 = expf(lg2 - mx);
        float ssum = e1 + e2;
        #pragma unroll
        for (int m = 1; m < 8; m <<= 1) ssum += __shfl_xor(ssum, m);
        attn_s[q * 128 + h * 16 + k1] = e1 / ssum;
        attn_s[q * 128 + h * 16 + k2] = e2 / ssum;

        float o[4] = {0.f, 0.f, 0.f, 0.f};
        for (int k = 0; k < NK; ++k) {
            const int ik = __shfl(tidx[qiq], srcb + k);
            const float* vr = vall + (rowb + ik) * DM;
            #pragma unroll
            for (int j = 0; j < 4; ++j) {
                int d = lane + 64 * j;
                o[j] = fmaf(attn_s[q * 128 + (d >> 5) * 16 + k], vr[d], o[j]);
            }
        }
        #pragma unroll
        for (int j = 0; j < 4; ++j) o8[q * 260 + lane + 64 * j] = o[j];
    }
    __syncthreads();

    {
        short8 ao[8];
        #pragma unroll
        for (int kk = 0; kk < 8; ++kk) {
            #pragma unroll
            for (int j = 0; j < 8; ++j) {
                int k = kk * 32 + quad * 8 + j;
                ao[kk][j] = (short)f2bf(o8[lr * 260 + k]);
            }
        }
        floatx4 aw[4];
        #pragma unroll
        for (int nt = 0; nt < 4; ++nt) aw[nt] = (floatx4){0.f, 0.f, 0.f, 0.f};
        #pragma unroll
        for (int nt = 0; nt < 4; ++nt) {
            #pragma unroll
            for (int kk = 0; kk < 8; ++kk) {
                short8 bofr = *(const short8*)(Wof + ((size_t)(((wave * 4 + nt) * 8 + kk) * 64) + lane) * 8);
                aw[nt] = __builtin_amdgcn_mfma_f32_16x16x32_bf16(ao[kk], bofr, aw[nt], 0, 0, 0);
            }
        }
        float rwv = rw[0];
        #pragma unroll
        for (int nt = 0; nt < 4; ++nt) {
            int col = (wave * 4 + nt) * 16 + lr;
            float bov = bo[col];
            #pragma unroll
            for (int reg = 0; reg < 4; ++reg) {
                int row = quad * 4 + reg;
                size_t t = tq0 + row;
                out[t * DM + col] = x[t * DM + col] + (aw[nt][reg] + bov) * rwv;
            }
        }
    }
}

// ---------------------------------------------------------------------------
// Kernel C: FFN — 32 tokens/block, 512 threads, LDS overlay (unchanged R8).
// ---------------------------------------------------------------------------
__global__ __launch_bounds__(512, 4) void ffn_kernel(
    float* __restrict__ io,
    const float* __restrict__ gf, const float* __restrict__ bf,
    const unsigned short* __restrict__ W1f, const float* __restrict__ b1f,
    const unsigned short* __restrict__ W2f, const float* __restrict__ b2f,
    const float* __restrict__ rw)
{
    __shared__ __align__(16) char pool[66048];
    __shared__ float gfs[256], bfs[256], b2s[256], b1s[1024];
    __shared__ float stat_m[32], stat_r[32];

    float (*xs)[260] = (float(*)[260])pool;                                  // 33280 B
    unsigned short (*Af)[8 * 64 * 8] = (unsigned short(*)[8 * 64 * 8])(pool + 33280); // 16384 B
    unsigned short (*G)[1032] = (unsigned short(*)[1032])pool;               // 66048 B (overlay)

    const int tid = threadIdx.x;
    const int lane = tid & 63, wave = tid >> 6;      // 8 waves
    const int quad = lane >> 4, lr = lane & 15;
    const size_t t0 = (size_t)blockIdx.x * 32;

    for (int i = tid; i < 32 * 256; i += 512) xs[i >> 8][i & 255] = io[t0 * DM + i];
    if (tid < 256) { gfs[tid] = gf[tid]; bfs[tid] = bf[tid]; b2s[tid] = b2f[tid]; }
    for (int i = tid; i < 1024; i += 512) b1s[i] = b1f[i];
    __syncthreads();

    {
        int tok = tid >> 4, l = tid & 15;
        float s = 0.f, s2 = 0.f;
        #pragma unroll
        for (int i = 0; i < 16; ++i) {
            float v = xs[tok][l + 16 * i];
            s += v; s2 += v * v;
        }
        #pragma unroll
        for (int m = 1; m < 16; m <<= 1) { s += __shfl_xor(s, m); s2 += __shfl_xor(s2, m); }
        if (l == 0) {
            float mean = s * (1.f / 256.f);
            float var  = s2 * (1.f / 256.f) - mean * mean;
            stat_m[tok] = mean;
            stat_r[tok] = rsqrtf(var + 1e-5f);
        }
    }
    __syncthreads();

    // A-fragments: row-tile rt = wave>>2, kk = (wave&3), (wave&3)+4
    {
        const int rt = wave >> 2;
        for (int kk = wave & 3; kk < 8; kk += 4) {
            int m = rt * 16 + lr, k0 = kk * 32 + quad * 8;
            float mm = stat_m[m], rr = stat_r[m];
            unsigned int pk[4];
            #pragma unroll
            for (int jj = 0; jj < 4; ++jj) {
                int ka = k0 + 2 * jj, kb = ka + 1;
                float v0 = (xs[m][ka] - mm) * rr * gfs[ka] + bfs[ka];
                float v1 = (xs[m][kb] - mm) * rr * gfs[kb] + bfs[kb];
                pk[jj] = (unsigned int)f2bf(v0) | ((unsigned int)f2bf(v1) << 16);
            }
            *(uint4*)&Af[rt][(kk * 64 + lane) * 8] = make_uint4(pk[0], pk[1], pk[2], pk[3]);
        }
    }
    __syncthreads();

    short8 afr[2][8];
    #pragma unroll
    for (int rt = 0; rt < 2; ++rt)
        #pragma unroll
        for (int kk = 0; kk < 8; ++kk)
            afr[rt][kk] = *(const short8*)&Af[rt][(kk * 64 + lane) * 8];
    __syncthreads();    // all xs/Af reads done before G overlays the pool

    // GEMM1: wave owns col-tiles (wave*8+nt), nt=0..7; B shared across 2 row-tiles
    for (int nt = 0; nt < 8; ++nt) {
        floatx4 acc0 = (floatx4){0.f, 0.f, 0.f, 0.f};
        floatx4 acc1 = (floatx4){0.f, 0.f, 0.f, 0.f};
        const int ntg = wave * 8 + nt;
        #pragma unroll
        for (int kk = 0; kk < 8; ++kk) {
            short8 bfr = *(const short8*)(W1f + (size_t)((ntg * 8 + kk) * 64 + lane) * 8);
            acc0 = __builtin_amdgcn_mfma_f32_16x16x32_bf16(afr[0][kk], bfr, acc0, 0, 0, 0);
            acc1 = __builtin_amdgcn_mfma_f32_16x16x32_bf16(afr[1][kk], bfr, acc1, 0, 0, 0);
        }
        const int n = ntg * 16 + lr;
        const float bb = b1s[n];
        #pragma unroll
        for (int reg = 0; reg < 4; ++reg) {
            int row = quad * 4 + reg;
            G[row][n]      = f2bf(gelu_fast(acc0[reg] + bb));
            G[row + 16][n] = f2bf(gelu_fast(acc1[reg] + bb));
        }
    }
    __syncthreads();

    // GEMM2: wave owns col-tiles (wave*2+nt2), nt2=0..1; B shared across rows
    floatx4 acc2[2][2];
    #pragma unroll
    for (int nt2 = 0; nt2 < 2; ++nt2)
        #pragma unroll
        for (int rt = 0; rt < 2; ++rt)
            acc2[nt2][rt] = (floatx4){0.f, 0.f, 0.f, 0.f};

    for (int kk2 = 0; kk2 < 32; ++kk2) {
        short8 a20 = *(const short8*)&G[lr][kk2 * 32 + quad * 8];
        short8 a21 = *(const short8*)&G[16 + lr][kk2 * 32 + quad * 8];
        #pragma unroll
        for (int nt2 = 0; nt2 < 2; ++nt2) {
            short8 b2 = *(const short8*)(W2f + (size_t)((((wave * 2 + nt2) * 32 + kk2) * 64 + lane) * 8));
            acc2[nt2][0] = __builtin_amdgcn_mfma_f32_16x16x32_bf16(a20, b2, acc2[nt2][0], 0, 0, 0);
            acc2[nt2][1] = __builtin_amdgcn_mfma_f32_16x16x32_bf16(a21, b2, acc2[nt2][1], 0, 0, 0);
        }
    }

    float rwv = rw[0];
    #pragma unroll
    for (int nt2 = 0; nt2 < 2; ++nt2) {
        int col = (wave * 2 + nt2) * 16 + lr;
        float bb = b2s[col];
        #pragma unroll
        for (int rt = 0; rt < 2; ++rt) {
            #pragma unroll
            for (int reg = 0; reg < 4; ++reg) {
                int row = rt * 16 + quad * 4 + reg;
                float o = acc2[nt2][rt][reg] + bb;
                size_t idx = (t0 + row) * DM + col;
                io[idx] = io[idx] + o * rwv;   // fresh re-read = original value
            }
        }
    }
}

// ---------------------------------------------------------------------------
extern "C" void kernel_launch(void* const* d_in, const int* in_sizes, int n_in,
                              void* d_out, int out_size, void* d_ws, size_t ws_size,
                              hipStream_t stream)
{
    const float* x   = (const float*)d_in[0];
    const float* Wq  = (const float*)d_in[1];
    const float* bq  = (const float*)d_in[2];
    const float* Wk  = (const float*)d_in[3];
    const float* bk  = (const float*)d_in[4];
    const float* Wv  = (const float*)d_in[5];
    const float* bv  = (const float*)d_in[6];
    const float* Wo  = (const float*)d_in[7];
    const float* bo  = (const float*)d_in[8];
    const float* g1  = (const float*)d_in[9];
    const float* b1  = (const float*)d_in[10];
    const float* gf  = (const float*)d_in[11];
    const float* bf  = (const float*)d_in[12];
    const float* W1  = (const float*)d_in[13];
    const float* b1f = (const float*)d_in[14];
    const float* W2  = (const float*)d_in[15];
    const float* b2f = (const float*)d_in[16];
    const float* rw  = (const float*)d_in[17];
    float* out = (float*)d_out;

    // workspace (~43.3 MB): qn | kn | knTh/knTl | vall | knsq | W1f | W2f | Wvf | Wof
    float* ws   = (float*)d_ws;
    float* qn   = ws;                          // 2,097,152 floats
    float* kn   = ws + 2097152;                // 2,097,152
    unsigned short* knTh = (unsigned short*)(ws + 4194304);  // 2,097,152 shorts (4MB)
    unsigned short* knTl = knTh + 2097152;                   // 2,097,152 shorts (4MB)
    float* vall = ws + 6291456;                // 4,194,304
    float* knsq = ws + 10485760;               // 16,384
    unsigned short* W1f = (unsigned short*)(ws + 10502144);   // 262,144 shorts
    unsigned short* W2f = W1f + 262144;                       // 262,144
    unsigned short* Wvf = W2f + 262144;                       // 65,536
    unsigned short* Wof = Wvf + 65536;                        // 65,536

    // WqT/WkT (128x256 fp32 each) live in the vall slot: conv writes them,
    // proj_qk reads them, then proj_v overwrites vall (stream-ordered).
    float* WqT = vall;                          // 32,768 floats
    float* WkT = vall + 32768;                  // 32,768 floats

    conv_kernel<<<576, 256, 0, stream>>>(W1, W2, Wv, Wo, Wq, Wk,
                                         W1f, W2f, Wvf, Wof, WqT, WkT);
    proj_qk_kernel<<<BATCH * SEQ / 8, 256, 0, stream>>>(x, WqT, bq, WkT, bk,
                                                        qn, kn, knTh, knTl, knsq);
    proj_v_kernel<<<BATCH * SEQ / 16, 256, 0, stream>>>(x, bv, g1, b1, Wvf, vall);
    attn_kernel<<<BATCH * SEQ / 16, 256, 0, stream>>>(x, qn, kn, knTh, knTl, knsq, vall,
                                                      Wof, bo, rw, out);
    ffn_kernel<<<BATCH * SEQ / 32, 512, 0, stream>>>(out, gf, bf, W1f, b1f, W2f, b2f, rw);
}

// Round 10
// 352.466 us; speedup vs baseline: 1.1854x; 1.1854x over previous
//
#include <hip/hip_runtime.h>
#include <math.h>

#define BATCH 8
#define SEQ   2048
#define DM    256
#define DQK   128
#define NHEADS 8
#define NK    16
#define DFF   1024

typedef __attribute__((ext_vector_type(8))) short short8;
typedef __attribute__((ext_vector_type(8))) _Float16 half8;
typedef __attribute__((ext_vector_type(4))) float floatx4;
typedef unsigned long long ull;

__device__ __forceinline__ unsigned short f2bf(float f) {
    unsigned int u = __float_as_uint(f);
    u += 0x7fffu + ((u >> 16) & 1u);          // round-to-nearest-even
    return (unsigned short)(u >> 16);
}

__device__ __forceinline__ float gelu_fast(float h) {
    float y = 0.7978845608028654f * (h + 0.044715f * h * h * h);
    float e = __expf(2.f * y);
    float t = 1.f - 2.f / (e + 1.f);
    return 0.5f * h * (1.f + t);
}

// composite sort key: primary score desc, secondary idx asc. Unique per idx.
__device__ __forceinline__ ull mkkey(float f, int gidx) {
    unsigned int u = __float_as_uint(f);
    u ^= (unsigned int)((int)u >> 31) | 0x80000000u;   // sortable float
    return ((ull)u << 32) | (unsigned int)(2047 - gidx);
}

__device__ __forceinline__ ull shfl_xor_u64(ull v, int m) {
    unsigned int lo = (unsigned int)v, hi = (unsigned int)(v >> 32);
    lo = __shfl_xor(lo, m);
    hi = __shfl_xor(hi, m);
    return ((ull)hi << 32) | lo;
}

// ---------------------------------------------------------------------------
// Kernel W: repack W1/W2/Wv/Wo fp32 -> bf16 MFMA B-fragment order (R8 verbatim).
// ---------------------------------------------------------------------------
__global__ __launch_bounds__(256) void conv_kernel(
    const float* __restrict__ W1, const float* __restrict__ W2,
    const float* __restrict__ Wv, const float* __restrict__ Wo,
    unsigned short* __restrict__ W1f, unsigned short* __restrict__ W2f,
    unsigned short* __restrict__ Wvf, unsigned short* __restrict__ Wof)
{
    int g = blockIdx.x * 256 + threadIdx.x;
    const float* W; unsigned short* O; int e, stride;
    if (g < 32768)      { W = W1; O = W1f; e = g;         stride = DFF; }
    else if (g < 65536) { W = W2; O = W2f; e = g - 32768; stride = DM;  }
    else if (g < 73728) { W = Wv; O = Wvf; e = g - 65536; stride = DM;  }
    else                { W = Wo; O = Wof; e = g - 73728; stride = DM;  }
    int lane = e & 63;
    int kk, nt;
    if (g < 32768)      { kk = (e >> 6) & 7;  nt = e >> 9;  }
    else if (g < 65536) { kk = (e >> 6) & 31; nt = e >> 11; }
    else                { kk = (e >> 6) & 7;  nt = e >> 9;  }
    int n = nt * 16 + (lane & 15);
    int k0 = kk * 32 + (lane >> 4) * 8;
    unsigned int pk[4];
    #pragma unroll
    for (int jj = 0; jj < 4; ++jj) {
        unsigned short lo = f2bf(W[(size_t)(k0 + 2 * jj) * stride + n]);
        unsigned short hi = f2bf(W[(size_t)(k0 + 2 * jj + 1) * stride + n]);
        pk[jj] = (unsigned int)lo | ((unsigned int)hi << 16);
    }
    *(uint4*)(O + (size_t)e * 8) = make_uint4(pk[0], pk[1], pk[2], pk[3]);
}

// ---------------------------------------------------------------------------
// Kernel A1: q/k projections — R8 verbatim (coalesced scalar weight loads;
// direct wave-uniform global x reads). Bit-identical fp32 chain.
// ---------------------------------------------------------------------------
__global__ __launch_bounds__(256) void proj_qk_kernel(
    const float* __restrict__ x,
    const float* __restrict__ Wq, const float* __restrict__ bq,
    const float* __restrict__ Wk, const float* __restrict__ bk,
    float* __restrict__ qn, float* __restrict__ kn,
    unsigned short* __restrict__ knTh, unsigned short* __restrict__ knTl,
    float* __restrict__ knsq)
{
    __shared__ __align__(16) float ks[8 * 128];
    __shared__ float nred[8][2], kred[8][2], k2red[8][2];

    const int tid = threadIdx.x;
    const int b = blockIdx.x & 7;
    const int chunk = blockIdx.x >> 3;
    const size_t t0 = (size_t)b * SEQ + (size_t)chunk * 8;

    {
        const int col = tid & 127, half = tid >> 7;
        const int half_u = __builtin_amdgcn_readfirstlane(half);
        const float* xrow[4];
        #pragma unroll
        for (int t = 0; t < 4; ++t)
            xrow[t] = x + (t0 + (size_t)(half_u * 4 + t)) * DM;

        float qa[4] = {0.f, 0.f, 0.f, 0.f}, ka[4] = {0.f, 0.f, 0.f, 0.f};
        for (int d = 0; d < 256; d += 4) {
            float4 xv[4];
            #pragma unroll
            for (int t = 0; t < 4; ++t) xv[t] = *(const float4*)(xrow[t] + d);
            #pragma unroll
            for (int dd = 0; dd < 4; ++dd) {
                float wq = Wq[(d + dd) * DQK + col];
                float wk = Wk[(d + dd) * DQK + col];
                #pragma unroll
                for (int t = 0; t < 4; ++t) {
                    float xval = (dd == 0) ? xv[t].x : (dd == 1) ? xv[t].y
                               : (dd == 2) ? xv[t].z : xv[t].w;
                    qa[t] = fmaf(xval, wq, qa[t]);
                    ka[t] = fmaf(xval, wk, ka[t]);
                }
            }
        }
        #pragma unroll
        for (int t = 0; t < 4; ++t) { qa[t] += bq[col]; ka[t] += bk[col]; }

        const int sub = (tid >> 6) & 1;
        #pragma unroll
        for (int t = 0; t < 4; ++t) {
            float sq = qa[t] * qa[t], sk = ka[t] * ka[t];
            #pragma unroll
            for (int m = 1; m < 64; m <<= 1) { sq += __shfl_xor(sq, m); sk += __shfl_xor(sk, m); }
            if ((tid & 63) == 0) { nred[half * 4 + t][sub] = sq; kred[half * 4 + t][sub] = sk; }
        }
        __syncthreads();
        float kvv[4];
        #pragma unroll
        for (int t = 0; t < 4; ++t) {
            int tok = half * 4 + t;
            float nq = sqrtf(nred[tok][0] + nred[tok][1]);
            float nk = sqrtf(kred[tok][0] + kred[tok][1]);
            float qv = qa[t] / fmaxf(nq, 1e-12f);
            float kv = ka[t] / fmaxf(nk, 1e-12f);
            qn[(t0 + tok) * DQK + col] = qv;
            kn[(t0 + tok) * DQK + col] = kv;
            ks[tok * 128 + col] = kv;
            kvv[t] = kv;
        }
        #pragma unroll
        for (int t = 0; t < 4; ++t) {
            float s2 = kvv[t] * kvv[t];
            #pragma unroll
            for (int m = 1; m < 64; m <<= 1) s2 += __shfl_xor(s2, m);
            if ((tid & 63) == 0) k2red[half * 4 + t][sub] = s2;
        }
        __syncthreads();
        if (tid < 8) knsq[t0 + tid] = k2red[tid][0] + k2red[tid][1];
    }

    // --- K^T -> fp16 hi/lo B-fragments ---
    {
        const int e   = tid & 127;
        const int sel = tid >> 7;           // 0 = hi, 1 = lo(*4096)
        const int key = e & 7;
        const int kq  = e >> 3;             // kk*4 + qd
        const int kk  = kq >> 2, qd = kq & 3;
        const int nt  = chunk >> 1;
        const int n   = ((chunk & 1) << 3) + key;
        const float* src = &ks[key * 128 + kk * 32 + qd * 8];
        unsigned int pk[4];
        #pragma unroll
        for (int jj = 0; jj < 4; ++jj) {
            float v0 = src[2 * jj], v1 = src[2 * jj + 1];
            _Float16 h0 = (_Float16)v0, h1 = (_Float16)v1;
            unsigned short u0, u1;
            if (sel == 0) {
                u0 = __builtin_bit_cast(unsigned short, h0);
                u1 = __builtin_bit_cast(unsigned short, h1);
            } else {
                _Float16 l0 = (_Float16)((v0 - (float)h0) * 4096.f);
                _Float16 l1 = (_Float16)((v1 - (float)h1) * 4096.f);
                u0 = __builtin_bit_cast(unsigned short, l0);
                u1 = __builtin_bit_cast(unsigned short, l1);
            }
            pk[jj] = (unsigned int)u0 | ((unsigned int)u1 << 16);
        }
        unsigned short* dst = (sel ? knTl : knTh)
            + (size_t)b * 262144
            + (size_t)((nt * 4 + kk) * 64 + qd * 16 + n) * 8;
        *(uint4*)dst = make_uint4(pk[0], pk[1], pk[2], pk[3]);
    }
}

// ---------------------------------------------------------------------------
// Kernel A2: v projection via bf16 MFMA (unchanged — passing).
// ---------------------------------------------------------------------------
__global__ __launch_bounds__(256) void proj_v_kernel(
    const float* __restrict__ x,
    const float* __restrict__ bv, const float* __restrict__ g1,
    const float* __restrict__ b1,
    const unsigned short* __restrict__ Wvf, float* __restrict__ vall)
{
    __shared__ __align__(16) float xs[16][260];
    __shared__ float stat_m[16], stat_r[16];
    __shared__ float bvs[256], g1s[256], b1s[256];

    const int tid = threadIdx.x;
    const int lane = tid & 63, wave = tid >> 6;
    const int quad = lane >> 4, lr = lane & 15;
    const size_t t0 = (size_t)blockIdx.x * 16;

    for (int i = tid; i < 16 * 256; i += 256) xs[i >> 8][i & 255] = x[t0 * DM + i];
    bvs[tid] = bv[tid]; g1s[tid] = g1[tid]; b1s[tid] = b1[tid];
    __syncthreads();

    {
        int tok = tid >> 4, l = tid & 15;
        float s = 0.f, s2 = 0.f;
        #pragma unroll
        for (int i = 0; i < 16; ++i) {
            float v = xs[tok][l + 16 * i];
            s += v; s2 += v * v;
        }
        #pragma unroll
        for (int m = 1; m < 16; m <<= 1) { s += __shfl_xor(s, m); s2 += __shfl_xor(s2, m); }
        if (l == 0) {
            float mean = s * (1.f / 256.f);
            float var  = s2 * (1.f / 256.f) - mean * mean;
            stat_m[tok] = mean;
            stat_r[tok] = rsqrtf(var + 1e-5f);
        }
    }
    __syncthreads();

    short8 av[8];
    {
        float mm = stat_m[lr], rr = stat_r[lr];
        #pragma unroll
        for (int kk = 0; kk < 8; ++kk) {
            #pragma unroll
            for (int j = 0; j < 8; ++j) {
                int k = kk * 32 + quad * 8 + j;
                float v = (xs[lr][k] - mm) * rr * g1s[k] + b1s[k];
                av[kk][j] = (short)f2bf(v);
            }
        }
    }
    floatx4 acc[4];
    #pragma unroll
    for (int nt = 0; nt < 4; ++nt) acc[nt] = (floatx4){0.f, 0.f, 0.f, 0.f};
    #pragma unroll
    for (int nt = 0; nt < 4; ++nt) {
        #pragma unroll
        for (int kk = 0; kk < 8; ++kk) {
            short8 bfr = *(const short8*)(Wvf + ((size_t)(((wave * 4 + nt) * 8 + kk) * 64) + lane) * 8);
            acc[nt] = __builtin_amdgcn_mfma_f32_16x16x32_bf16(av[kk], bfr, acc[nt], 0, 0, 0);
        }
    }
    #pragma unroll
    for (int nt = 0; nt < 4; ++nt) {
        int col = (wave * 4 + nt) * 16 + lr;
        float bb = bvs[col];
        #pragma unroll
        for (int reg = 0; reg < 4; ++reg) {
            int row = quad * 4 + reg;
            vall[(t0 + row) * DM + col] = acc[nt][reg] + bb;
        }
    }
}

// ---------------------------------------------------------------------------
// Kernel B: attn, 16 queries/block. Scores/merge exactness unchanged; the
// selection now runs on 16-LANE subgroups (= quad/lr): each thread owns ONE
// query per quarter -> butterfly depth 5->4, rounds/thread halved (~60% less
// serial shuffle chain). Candidates in 4 named regs (static indexing); merge
// = 5-compare sort network + 16 rounds x 4 stages. topidx bit-identical.
// ---------------------------------------------------------------------------
__global__ __launch_bounds__(256, 4) void attn_kernel(
    const float* __restrict__ x,
    const float* __restrict__ qn_g, const float* __restrict__ kn_g,
    const unsigned short* __restrict__ knTh, const unsigned short* __restrict__ knTl,
    const float* __restrict__ knsq_g,
    const float* __restrict__ vall,
    const unsigned short* __restrict__ Wof, const float* __restrict__ bo,
    const float* __restrict__ rw, float* __restrict__ out)
{
    __shared__ __align__(16) float s_ld[16 * 512];      // exactly 32KB
    float* attn_s = s_ld;            // 16*128 floats
    float* o8     = s_ld + 2048;     // 16*260 floats (stride 260: conflict-free)

    const int tid = threadIdx.x;
    const int lane = tid & 63, wave = tid >> 6;
    const int quad = lane >> 4, lr = lane & 15;   // 16-lane subgroup: quad = sg, lr = lane-in-sg
    const int sgid = wave * 4 + quad;             // 0..15: query this subgroup selects for
    const int b = blockIdx.x & 7;
    const int chunk = blockIdx.x >> 3;            // 0..127
    const size_t tq0 = (size_t)b * SEQ + (size_t)chunk * 16;
    const size_t rowb = (size_t)b * SEQ;

    // ---- Q A-fragments, fp16 hi/lo, straight from global (16 real rows) ----
    half8 a_hi[4], a_lo[4];
    {
        const float* qrow = qn_g + (tq0 + lr) * DQK + quad * 8;
        #pragma unroll
        for (int kk = 0; kk < 4; ++kk) {
            float4 fa = *(const float4*)(qrow + kk * 32);
            float4 fb = *(const float4*)(qrow + kk * 32 + 4);
            float vv[8] = {fa.x, fa.y, fa.z, fa.w, fb.x, fb.y, fb.z, fb.w};
            #pragma unroll
            for (int j = 0; j < 8; ++j) {
                float v = vv[j];
                _Float16 h = (_Float16)v;
                a_hi[kk][j] = h;
                a_lo[kk][j] = (_Float16)((v - (float)h) * 4096.f);
            }
        }
    }

    const unsigned short* bh = knTh + (size_t)b * 262144;
    const unsigned short* bl = knTl + (size_t)b * 262144;
    const float* ksqb = knsq_g + rowb;

    ull cqa = 0, cqb = 0, cqc = 0, cqd = 0;   // per-quarter candidate regs (named)

    for (int q4 = 0; q4 < 4; ++q4) {
        if (q4) __syncthreads();         // prev quarter's selection done with s_ld

        // ---- scores: q.k = hi.hi + (hi.lo' + lo'.hi)/4096 ----
        for (int t = 0; t < 8; ++t) {
            const int tile = q4 * 32 + wave * 8 + t;
            const unsigned short* ph = bh + (size_t)tile * 2048 + lane * 8;
            const unsigned short* pl = bl + (size_t)tile * 2048 + lane * 8;
            floatx4 am  = (floatx4){0.f, 0.f, 0.f, 0.f};
            floatx4 ax1 = (floatx4){0.f, 0.f, 0.f, 0.f};
            floatx4 ax2 = (floatx4){0.f, 0.f, 0.f, 0.f};
            #pragma unroll
            for (int kk = 0; kk < 4; ++kk) {
                half8 bhf = *(const half8*)(ph + kk * 512);
                half8 blf = *(const half8*)(pl + kk * 512);
                am  = __builtin_amdgcn_mfma_f32_16x16x32_f16(a_hi[kk], bhf, am,  0, 0, 0);
                ax1 = __builtin_amdgcn_mfma_f32_16x16x32_f16(a_hi[kk], blf, ax1, 0, 0, 0);
                ax2 = __builtin_amdgcn_mfma_f32_16x16x32_f16(a_lo[kk], bhf, ax2, 0, 0, 0);
            }
            const int keyloc = (wave * 8 + t) * 16 + lr;
            const float kq = ksqb[q4 * 512 + keyloc];
            #pragma unroll
            for (int r = 0; r < 4; ++r) {
                s_ld[(quad * 4 + r) * 512 + keyloc] =
                    2.f * (am[r] + (ax1[r] + ax2[r]) * (1.f / 4096.f)) - kq;
            }
        }
        __syncthreads();

        // ---- per-quarter top-16 (exact tournament, 1 query / 16-lane sg) ----
        {
            const float* srow = &s_ld[sgid * 512 + lr];
            // stream: exact composite top-2 per lane (strict >, ascending gidx)
            float f0 = -INFINITY, f1 = -INFINITY;
            int   i0 = 0, i1 = 0;
            #pragma unroll
            for (int i = 0; i < 32; ++i) {
                float f = srow[16 * i];
                int gidx = q4 * 512 + lr + 16 * i;
                bool a  = f > f0;
                bool bb = f > f1;
                f1 = a ? f0 : (bb ? f    : f1);
                i1 = a ? i0 : (bb ? gidx : i1);
                f0 = a ? f    : f0;
                i0 = a ? gidx : i0;
            }
            ull k2v = mkkey(f1, i1);
            ull cur = mkkey(f0, i0);
            int cnt = 0;
            for (int r = 0; r < NK; ++r) {
                ull w = cur;
                #pragma unroll
                for (int m = 1; m < 16; m <<= 1) {
                    ull o = shfl_xor_u64(w, m);
                    if (o > w) w = o;
                }
                if (lr == r) {          // lane r captures rank r of quarter q4
                    if (q4 == 0) cqa = w; else if (q4 == 1) cqb = w;
                    else if (q4 == 2) cqc = w; else cqd = w;
                }
                if (cur == w) {                      // unique key -> one lane pops
                    ++cnt;
                    if (cnt == 1) cur = k2v;
                    else {
                        // rare: 3rd+ pop from this lane -> exact rescan for
                        // max composite key strictly below the one just popped
                        ull best = 0;
                        for (int i = 0; i < 32; ++i) {
                            float f = srow[16 * i];
                            ull k = mkkey(f, q4 * 512 + lr + 16 * i);
                            if (k < w && k > best) best = k;
                        }
                        cur = best;
                    }
                }
            }
        }
    }
    __syncthreads();   // last quarter's selection done reading s_ld

    // ---- exact merge: 64 candidates (4/lane, 16 lanes) -> top-16 in order ----
    int tidx = 0;      // lane lr of subgroup quad holds rank lr for query sgid
    {
        ull c0 = cqa, c1 = cqb, c2 = cqc, c3 = cqd;
        // sort c0..c3 descending (5-compare network)
        { ull t; if (c1 > c0) { t = c0; c0 = c1; c1 = t; }
                 if (c3 > c2) { t = c2; c2 = c3; c3 = t; }
                 if (c2 > c0) { t = c0; c0 = c2; c2 = t; }
                 if (c3 > c1) { t = c1; c1 = c3; c3 = t; }
                 if (c2 > c1) { t = c1; c1 = c2; c2 = t; } }
        ull cur = c0; int nxt = 1;
        for (int r = 0; r < NK; ++r) {
            ull w = cur;
            #pragma unroll
            for (int m = 1; m < 16; m <<= 1) {
                ull o = shfl_xor_u64(w, m);
                if (o > w) w = o;
            }
            if (lr == r) tidx = 2047 - (int)(unsigned int)(w & 0xFFFFFFFFull);
            if (cur == w) {
                cur = (nxt == 1) ? c1 : (nxt == 2) ? c2 : (nxt == 3) ? c3 : 0ull;
                ++nxt;
            }
        }
    }

    // ---- softmax + PV: wave processes its own 4 subgroups' queries ----
    // wave w -> queries {4w..4w+3}; rank-k index via __shfl from lane qq*16+k.
    #pragma unroll
    for (int qq = 0; qq < 4; ++qq) {
        const int q = wave * 4 + qq;
        const int srcb = qq * 16;
        const int h = lane >> 3;
        const int k1 = lane & 7, k2 = 8 + (lane & 7);
        const int i1 = __shfl(tidx, srcb + k1);
        const int i2 = __shfl(tidx, srcb + k2);
        const float* qrow = qn_g + (tq0 + q) * DQK + h * 16;
        const float* kr1 = kn_g + (rowb + i1) * DQK + h * 16;
        const float* kr2 = kn_g + (rowb + i2) * DQK + h * 16;
        float lg1 = 0.f, lg2 = 0.f;
        #pragma unroll
        for (int d = 0; d < 16; d += 4) {
            float4 qv = *(const float4*)&qrow[d];
            float4 a1 = *(const float4*)&kr1[d];
            float4 a2 = *(const float4*)&kr2[d];
            lg1 = fmaf(qv.x, a1.x, lg1); lg1 = fmaf(qv.y, a1.y, lg1);
            lg1 = fmaf(qv.z, a1.z, lg1); lg1 = fmaf(qv.w, a1.w, lg1);
            lg2 = fmaf(qv.x, a2.x, lg2); lg2 = fmaf(qv.y, a2.y, lg2);
            lg2 = fmaf(qv.z, a2.z, lg2); lg2 = fmaf(qv.w, a2.w, lg2);
        }
        lg1 *= 0.25f; lg2 *= 0.25f;
        float mx = fmaxf(lg1, lg2);
        #pragma unroll
        for (int m = 1; m < 8; m <<= 1) mx = fmaxf(mx, __shfl_xor(mx, m));
        float e1 = expf(lg1 - mx), e2 = expf(lg2 - mx);
        float ssum = e1 + e2;
        #pragma unroll
        for (int m = 1; m < 8; m <<= 1) ssum += __shfl_xor(ssum, m);
        attn_s[q * 128 + h * 16 + k1] = e1 / ssum;
        attn_s[q * 128 + h * 16 + k2] = e2 / ssum;
        // within-wave LDS RAW: ordered by lgkmcnt, no barrier needed

        float o[4] = {0.f, 0.f, 0.f, 0.f};
        for (int k = 0; k < NK; ++k) {
            const int ik = __shfl(tidx, srcb + k);
            const float* vr = vall + (rowb + ik) * DM;
            #pragma unroll
            for (int j = 0; j < 4; ++j) {
                int d = lane + 64 * j;
                o[j] = fmaf(attn_s[q * 128 + (d >> 5) * 16 + k], vr[d], o[j]);
            }
        }
        #pragma unroll
        for (int j = 0; j < 4; ++j) o8[q * 260 + lane + 64 * j] = o[j];
    }
    __syncthreads();    // o8 is read cross-wave in the Wo phase

    // ---- phase 3b: Wo via bf16 MFMA, 16 real rows.
    {
        short8 ao[8];
        #pragma unroll
        for (int kk = 0; kk < 8; ++kk) {
            #pragma unroll
            for (int j = 0; j < 8; ++j) {
                int k = kk * 32 + quad * 8 + j;
                ao[kk][j] = (short)f2bf(o8[lr * 260 + k]);
            }
        }
        floatx4 aw[4];
        #pragma unroll
        for (int nt = 0; nt < 4; ++nt) aw[nt] = (floatx4){0.f, 0.f, 0.f, 0.f};
        #pragma unroll
        for (int nt = 0; nt < 4; ++nt) {
            #pragma unroll
            for (int kk = 0; kk < 8; ++kk) {
                short8 bofr = *(const short8*)(Wof + ((size_t)(((wave * 4 + nt) * 8 + kk) * 64) + lane) * 8);
                aw[nt] = __builtin_amdgcn_mfma_f32_16x16x32_bf16(ao[kk], bofr, aw[nt], 0, 0, 0);
            }
        }
        float rwv = rw[0];
        #pragma unroll
        for (int nt = 0; nt < 4; ++nt) {
            int col = (wave * 4 + nt) * 16 + lr;
            float bov = bo[col];
            #pragma unroll
            for (int reg = 0; reg < 4; ++reg) {
                int row = quad * 4 + reg;
                size_t t = tq0 + row;
                out[t * DM + col] = x[t * DM + col] + (aw[nt][reg] + bov) * rwv;
            }
        }
    }
}

// ---------------------------------------------------------------------------
// Kernel C: FFN — 32 tokens/block, 512 threads, LDS overlay (R8 verbatim).
// ---------------------------------------------------------------------------
__global__ __launch_bounds__(512, 4) void ffn_kernel(
    float* __restrict__ io,
    const float* __restrict__ gf, const float* __restrict__ bf,
    const unsigned short* __restrict__ W1f, const float* __restrict__ b1f,
    const unsigned short* __restrict__ W2f, const float* __restrict__ b2f,
    const float* __restrict__ rw)
{
    __shared__ __align__(16) char pool[66048];
    __shared__ float gfs[256], bfs[256], b2s[256], b1s[1024];
    __shared__ float stat_m[32], stat_r[32];

    float (*xs)[260] = (float(*)[260])pool;                                  // 33280 B
    unsigned short (*Af)[8 * 64 * 8] = (unsigned short(*)[8 * 64 * 8])(pool + 33280); // 16384 B
    unsigned short (*G)[1032] = (unsigned short(*)[1032])pool;               // 66048 B (overlay)

    const int tid = threadIdx.x;
    const int lane = tid & 63, wave = tid >> 6;      // 8 waves
    const int quad = lane >> 4, lr = lane & 15;
    const size_t t0 = (size_t)blockIdx.x * 32;

    for (int i = tid; i < 32 * 256; i += 512) xs[i >> 8][i & 255] = io[t0 * DM + i];
    if (tid < 256) { gfs[tid] = gf[tid]; bfs[tid] = bf[tid]; b2s[tid] = b2f[tid]; }
    for (int i = tid; i < 1024; i += 512) b1s[i] = b1f[i];
    __syncthreads();

    {
        int tok = tid >> 4, l = tid & 15;
        float s = 0.f, s2 = 0.f;
        #pragma unroll
        for (int i = 0; i < 16; ++i) {
            float v = xs[tok][l + 16 * i];
            s += v; s2 += v * v;
        }
        #pragma unroll
        for (int m = 1; m < 16; m <<= 1) { s += __shfl_xor(s, m); s2 += __shfl_xor(s2, m); }
        if (l == 0) {
            float mean = s * (1.f / 256.f);
            float var  = s2 * (1.f / 256.f) - mean * mean;
            stat_m[tok] = mean;
            stat_r[tok] = rsqrtf(var + 1e-5f);
        }
    }
    __syncthreads();

    // A-fragments: row-tile rt = wave>>2, kk = (wave&3), (wave&3)+4
    {
        const int rt = wave >> 2;
        for (int kk = wave & 3; kk < 8; kk += 4) {
            int m = rt * 16 + lr, k0 = kk * 32 + quad * 8;
            float mm = stat_m[m], rr = stat_r[m];
            unsigned int pk[4];
            #pragma unroll
            for (int jj = 0; jj < 4; ++jj) {
                int ka = k0 + 2 * jj, kb = ka + 1;
                float v0 = (xs[m][ka] - mm) * rr * gfs[ka] + bfs[ka];
                float v1 = (xs[m][kb] - mm) * rr * gfs[kb] + bfs[kb];
                pk[jj] = (unsigned int)f2bf(v0) | ((unsigned int)f2bf(v1) << 16);
            }
            *(uint4*)&Af[rt][(kk * 64 + lane) * 8] = make_uint4(pk[0], pk[1], pk[2], pk[3]);
        }
    }
    __syncthreads();

    short8 afr[2][8];
    #pragma unroll
    for (int rt = 0; rt < 2; ++rt)
        #pragma unroll
        for (int kk = 0; kk < 8; ++kk)
            afr[rt][kk] = *(const short8*)&Af[rt][(kk * 64 + lane) * 8];
    __syncthreads();    // all xs/Af reads done before G overlays the pool

    // GEMM1: wave owns col-tiles (wave*8+nt), nt=0..7; B shared across 2 row-tiles
    for (int nt = 0; nt < 8; ++nt) {
        floatx4 acc0 = (floatx4){0.f, 0.f, 0.f, 0.f};
        floatx4 acc1 = (floatx4){0.f, 0.f, 0.f, 0.f};
        const int ntg = wave * 8 + nt;
        #pragma unroll
        for (int kk = 0; kk < 8; ++kk) {
            short8 bfr = *(const short8*)(W1f + (size_t)((ntg * 8 + kk) * 64 + lane) * 8);
            acc0 = __builtin_amdgcn_mfma_f32_16x16x32_bf16(afr[0][kk], bfr, acc0, 0, 0, 0);
            acc1 = __builtin_amdgcn_mfma_f32_16x16x32_bf16(afr[1][kk], bfr, acc1, 0, 0, 0);
        }
        const int n = ntg * 16 + lr;
        const float bb = b1s[n];
        #pragma unroll
        for (int reg = 0; reg < 4; ++reg) {
            int row = quad * 4 + reg;
            G[row][n]      = f2bf(gelu_fast(acc0[reg] + bb));
            G[row + 16][n] = f2bf(gelu_fast(acc1[reg] + bb));
        }
    }
    __syncthreads();

    // GEMM2: wave owns col-tiles (wave*2+nt2), nt2=0..1; B shared across rows
    floatx4 acc2[2][2];
    #pragma unroll
    for (int nt2 = 0; nt2 < 2; ++nt2)
        #pragma unroll
        for (int rt = 0; rt < 2; ++rt)
            acc2[nt2][rt] = (floatx4){0.f, 0.f, 0.f, 0.f};

    for (int kk2 = 0; kk2 < 32; ++kk2) {
        short8 a20 = *(const short8*)&G[lr][kk2 * 32 + quad * 8];
        short8 a21 = *(const short8*)&G[16 + lr][kk2 * 32 + quad * 8];
        #pragma unroll
        for (int nt2 = 0; nt2 < 2; ++nt2) {
            short8 b2 = *(const short8*)(W2f + (size_t)((((wave * 2 + nt2) * 32 + kk2) * 64 + lane) * 8));
            acc2[nt2][0] = __builtin_amdgcn_mfma_f32_16x16x32_bf16(a20, b2, acc2[nt2][0], 0, 0, 0);
            acc2[nt2][1] = __builtin_amdgcn_mfma_f32_16x16x32_bf16(a21, b2, acc2[nt2][1], 0, 0, 0);
        }
    }

    float rwv = rw[0];
    #pragma unroll
    for (int nt2 = 0; nt2 < 2; ++nt2) {
        int col = (wave * 2 + nt2) * 16 + lr;
        float bb = b2s[col];
        #pragma unroll
        for (int rt = 0; rt < 2; ++rt) {
            #pragma unroll
            for (int reg = 0; reg < 4; ++reg) {
                int row = rt * 16 + quad * 4 + reg;
                float o = acc2[nt2][rt][reg] + bb;
                size_t idx = (t0 + row) * DM + col;
                io[idx] = io[idx] + o * rwv;   // fresh re-read = original value
            }
        }
    }
}

// ---------------------------------------------------------------------------
extern "C" void kernel_launch(void* const* d_in, const int* in_sizes, int n_in,
                              void* d_out, int out_size, void* d_ws, size_t ws_size,
                              hipStream_t stream)
{
    const float* x   = (const float*)d_in[0];
    const float* Wq  = (const float*)d_in[1];
    const float* bq  = (const float*)d_in[2];
    const float* Wk  = (const float*)d_in[3];
    const float* bk  = (const float*)d_in[4];
    const float* Wv  = (const float*)d_in[5];
    const float* bv  = (const float*)d_in[6];
    const float* Wo  = (const float*)d_in[7];
    const float* bo  = (const float*)d_in[8];
    const float* g1  = (const float*)d_in[9];
    const float* b1  = (const float*)d_in[10];
    const float* gf  = (const float*)d_in[11];
    const float* bf  = (const float*)d_in[12];
    const float* W1  = (const float*)d_in[13];
    const float* b1f = (const float*)d_in[14];
    const float* W2  = (const float*)d_in[15];
    const float* b2f = (const float*)d_in[16];
    const float* rw  = (const float*)d_in[17];
    float* out = (float*)d_out;

    // workspace (~43.3 MB): qn | kn | knTh/knTl | vall | knsq | W1f | W2f | Wvf | Wof
    float* ws   = (float*)d_ws;
    float* qn   = ws;                          // 2,097,152 floats
    float* kn   = ws + 2097152;                // 2,097,152
    unsigned short* knTh = (unsigned short*)(ws + 4194304);  // 2,097,152 shorts (4MB)
    unsigned short* knTl = knTh + 2097152;                   // 2,097,152 shorts (4MB)
    float* vall = ws + 6291456;                // 4,194,304
    float* knsq = ws + 10485760;               // 16,384
    unsigned short* W1f = (unsigned short*)(ws + 10502144);   // 262,144 shorts
    unsigned short* W2f = W1f + 262144;                       // 262,144
    unsigned short* Wvf = W2f + 262144;                       // 65,536
    unsigned short* Wof = Wvf + 65536;                        // 65,536

    conv_kernel<<<320, 256, 0, stream>>>(W1, W2, Wv, Wo, W1f, W2f, Wvf, Wof);
    proj_qk_kernel<<<BATCH * SEQ / 8, 256, 0, stream>>>(x, Wq, bq, Wk, bk,
                                                        qn, kn, knTh, knTl, knsq);
    proj_v_kernel<<<BATCH * SEQ / 16, 256, 0, stream>>>(x, bv, g1, b1, Wvf, vall);
    attn_kernel<<<BATCH * SEQ / 16, 256, 0, stream>>>(x, qn, kn, knTh, knTl, knsq, vall,
                                                      Wof, bo, rw, out);
    ffn_kernel<<<BATCH * SEQ / 32, 512, 0, stream>>>(out, gf, bf, W1f, b1f, W2f, b2f, rw);
}

// Round 11
// 346.870 us; speedup vs baseline: 1.2045x; 1.0161x over previous
//
#include <hip/hip_runtime.h>
#include <math.h>

#define BATCH 8
#define SEQ   2048
#define DM    256
#define DQK   128
#define NHEADS 8
#define NK    16
#define DFF   1024

typedef __attribute__((ext_vector_type(8))) short short8;
typedef __attribute__((ext_vector_type(8))) _Float16 half8;
typedef __attribute__((ext_vector_type(4))) float floatx4;
typedef unsigned long long ull;

__device__ __forceinline__ unsigned short f2bf(float f) {
    unsigned int u = __float_as_uint(f);
    u += 0x7fffu + ((u >> 16) & 1u);          // round-to-nearest-even
    return (unsigned short)(u >> 16);
}

__device__ __forceinline__ float gelu_fast(float h) {
    float y = 0.7978845608028654f * (h + 0.044715f * h * h * h);
    float e = __expf(2.f * y);
    float t = 1.f - 2.f / (e + 1.f);
    return 0.5f * h * (1.f + t);
}

// composite sort key: primary score desc, secondary idx asc. Unique per idx.
__device__ __forceinline__ ull mkkey(float f, int gidx) {
    unsigned int u = __float_as_uint(f);
    u ^= (unsigned int)((int)u >> 31) | 0x80000000u;   // sortable float
    return ((ull)u << 32) | (unsigned int)(2047 - gidx);
}

__device__ __forceinline__ ull shfl_xor_u64(ull v, int m) {
    unsigned int lo = (unsigned int)v, hi = (unsigned int)(v >> 32);
    lo = __shfl_xor(lo, m);
    hi = __shfl_xor(hi, m);
    return ((ull)hi << 32) | lo;
}

// ---------------------------------------------------------------------------
// Kernel W: repack W1/W2/Wv/Wo fp32 -> bf16 MFMA B-fragment order (R8 verbatim).
// ---------------------------------------------------------------------------
__global__ __launch_bounds__(256) void conv_kernel(
    const float* __restrict__ W1, const float* __restrict__ W2,
    const float* __restrict__ Wv, const float* __restrict__ Wo,
    unsigned short* __restrict__ W1f, unsigned short* __restrict__ W2f,
    unsigned short* __restrict__ Wvf, unsigned short* __restrict__ Wof)
{
    int g = blockIdx.x * 256 + threadIdx.x;
    const float* W; unsigned short* O; int e, stride;
    if (g < 32768)      { W = W1; O = W1f; e = g;         stride = DFF; }
    else if (g < 65536) { W = W2; O = W2f; e = g - 32768; stride = DM;  }
    else if (g < 73728) { W = Wv; O = Wvf; e = g - 65536; stride = DM;  }
    else                { W = Wo; O = Wof; e = g - 73728; stride = DM;  }
    int lane = e & 63;
    int kk, nt;
    if (g < 32768)      { kk = (e >> 6) & 7;  nt = e >> 9;  }
    else if (g < 65536) { kk = (e >> 6) & 31; nt = e >> 11; }
    else                { kk = (e >> 6) & 7;  nt = e >> 9;  }
    int n = nt * 16 + (lane & 15);
    int k0 = kk * 32 + (lane >> 4) * 8;
    unsigned int pk[4];
    #pragma unroll
    for (int jj = 0; jj < 4; ++jj) {
        unsigned short lo = f2bf(W[(size_t)(k0 + 2 * jj) * stride + n]);
        unsigned short hi = f2bf(W[(size_t)(k0 + 2 * jj + 1) * stride + n]);
        pk[jj] = (unsigned int)lo | ((unsigned int)hi << 16);
    }
    *(uint4*)(O + (size_t)e * 8) = make_uint4(pk[0], pk[1], pk[2], pk[3]);
}

// ---------------------------------------------------------------------------
// Kernel A1: q/k projections — R8 verbatim (coalesced scalar weight loads;
// direct wave-uniform global x reads). Bit-identical fp32 chain.
// ---------------------------------------------------------------------------
__global__ __launch_bounds__(256) void proj_qk_kernel(
    const float* __restrict__ x,
    const float* __restrict__ Wq, const float* __restrict__ bq,
    const float* __restrict__ Wk, const float* __restrict__ bk,
    float* __restrict__ qn, float* __restrict__ kn,
    unsigned short* __restrict__ knTh, unsigned short* __restrict__ knTl,
    float* __restrict__ knsq)
{
    __shared__ __align__(16) float ks[8 * 128];
    __shared__ float nred[8][2], kred[8][2], k2red[8][2];

    const int tid = threadIdx.x;
    const int b = blockIdx.x & 7;
    const int chunk = blockIdx.x >> 3;
    const size_t t0 = (size_t)b * SEQ + (size_t)chunk * 8;

    {
        const int col = tid & 127, half = tid >> 7;
        const int half_u = __builtin_amdgcn_readfirstlane(half);
        const float* xrow[4];
        #pragma unroll
        for (int t = 0; t < 4; ++t)
            xrow[t] = x + (t0 + (size_t)(half_u * 4 + t)) * DM;

        float qa[4] = {0.f, 0.f, 0.f, 0.f}, ka[4] = {0.f, 0.f, 0.f, 0.f};
        for (int d = 0; d < 256; d += 4) {
            float4 xv[4];
            #pragma unroll
            for (int t = 0; t < 4; ++t) xv[t] = *(const float4*)(xrow[t] + d);
            #pragma unroll
            for (int dd = 0; dd < 4; ++dd) {
                float wq = Wq[(d + dd) * DQK + col];
                float wk = Wk[(d + dd) * DQK + col];
                #pragma unroll
                for (int t = 0; t < 4; ++t) {
                    float xval = (dd == 0) ? xv[t].x : (dd == 1) ? xv[t].y
                               : (dd == 2) ? xv[t].z : xv[t].w;
                    qa[t] = fmaf(xval, wq, qa[t]);
                    ka[t] = fmaf(xval, wk, ka[t]);
                }
            }
        }
        #pragma unroll
        for (int t = 0; t < 4; ++t) { qa[t] += bq[col]; ka[t] += bk[col]; }

        const int sub = (tid >> 6) & 1;
        #pragma unroll
        for (int t = 0; t < 4; ++t) {
            float sq = qa[t] * qa[t], sk = ka[t] * ka[t];
            #pragma unroll
            for (int m = 1; m < 64; m <<= 1) { sq += __shfl_xor(sq, m); sk += __shfl_xor(sk, m); }
            if ((tid & 63) == 0) { nred[half * 4 + t][sub] = sq; kred[half * 4 + t][sub] = sk; }
        }
        __syncthreads();
        float kvv[4];
        #pragma unroll
        for (int t = 0; t < 4; ++t) {
            int tok = half * 4 + t;
            float nq = sqrtf(nred[tok][0] + nred[tok][1]);
            float nk = sqrtf(kred[tok][0] + kred[tok][1]);
            float qv = qa[t] / fmaxf(nq, 1e-12f);
            float kv = ka[t] / fmaxf(nk, 1e-12f);
            qn[(t0 + tok) * DQK + col] = qv;
            kn[(t0 + tok) * DQK + col] = kv;
            ks[tok * 128 + col] = kv;
            kvv[t] = kv;
        }
        #pragma unroll
        for (int t = 0; t < 4; ++t) {
            float s2 = kvv[t] * kvv[t];
            #pragma unroll
            for (int m = 1; m < 64; m <<= 1) s2 += __shfl_xor(s2, m);
            if ((tid & 63) == 0) k2red[half * 4 + t][sub] = s2;
        }
        __syncthreads();
        if (tid < 8) knsq[t0 + tid] = k2red[tid][0] + k2red[tid][1];
    }

    // --- K^T -> fp16 hi/lo B-fragments ---
    {
        const int e   = tid & 127;
        const int sel = tid >> 7;           // 0 = hi, 1 = lo(*4096)
        const int key = e & 7;
        const int kq  = e >> 3;             // kk*4 + qd
        const int kk  = kq >> 2, qd = kq & 3;
        const int nt  = chunk >> 1;
        const int n   = ((chunk & 1) << 3) + key;
        const float* src = &ks[key * 128 + kk * 32 + qd * 8];
        unsigned int pk[4];
        #pragma unroll
        for (int jj = 0; jj < 4; ++jj) {
            float v0 = src[2 * jj], v1 = src[2 * jj + 1];
            _Float16 h0 = (_Float16)v0, h1 = (_Float16)v1;
            unsigned short u0, u1;
            if (sel == 0) {
                u0 = __builtin_bit_cast(unsigned short, h0);
                u1 = __builtin_bit_cast(unsigned short, h1);
            } else {
                _Float16 l0 = (_Float16)((v0 - (float)h0) * 4096.f);
                _Float16 l1 = (_Float16)((v1 - (float)h1) * 4096.f);
                u0 = __builtin_bit_cast(unsigned short, l0);
                u1 = __builtin_bit_cast(unsigned short, l1);
            }
            pk[jj] = (unsigned int)u0 | ((unsigned int)u1 << 16);
        }
        unsigned short* dst = (sel ? knTl : knTh)
            + (size_t)b * 262144
            + (size_t)((nt * 4 + kk) * 64 + qd * 16 + n) * 8;
        *(uint4*)dst = make_uint4(pk[0], pk[1], pk[2], pk[3]);
    }
}

// ---------------------------------------------------------------------------
// Kernel A2: v projection via bf16 MFMA (unchanged — passing).
// ---------------------------------------------------------------------------
__global__ __launch_bounds__(256) void proj_v_kernel(
    const float* __restrict__ x,
    const float* __restrict__ bv, const float* __restrict__ g1,
    const float* __restrict__ b1,
    const unsigned short* __restrict__ Wvf, float* __restrict__ vall)
{
    __shared__ __align__(16) float xs[16][260];
    __shared__ float stat_m[16], stat_r[16];
    __shared__ float bvs[256], g1s[256], b1s[256];

    const int tid = threadIdx.x;
    const int lane = tid & 63, wave = tid >> 6;
    const int quad = lane >> 4, lr = lane & 15;
    const size_t t0 = (size_t)blockIdx.x * 16;

    for (int i = tid; i < 16 * 256; i += 256) xs[i >> 8][i & 255] = x[t0 * DM + i];
    bvs[tid] = bv[tid]; g1s[tid] = g1[tid]; b1s[tid] = b1[tid];
    __syncthreads();

    {
        int tok = tid >> 4, l = tid & 15;
        float s = 0.f, s2 = 0.f;
        #pragma unroll
        for (int i = 0; i < 16; ++i) {
            float v = xs[tok][l + 16 * i];
            s += v; s2 += v * v;
        }
        #pragma unroll
        for (int m = 1; m < 16; m <<= 1) { s += __shfl_xor(s, m); s2 += __shfl_xor(s2, m); }
        if (l == 0) {
            float mean = s * (1.f / 256.f);
            float var  = s2 * (1.f / 256.f) - mean * mean;
            stat_m[tok] = mean;
            stat_r[tok] = rsqrtf(var + 1e-5f);
        }
    }
    __syncthreads();

    short8 av[8];
    {
        float mm = stat_m[lr], rr = stat_r[lr];
        #pragma unroll
        for (int kk = 0; kk < 8; ++kk) {
            #pragma unroll
            for (int j = 0; j < 8; ++j) {
                int k = kk * 32 + quad * 8 + j;
                float v = (xs[lr][k] - mm) * rr * g1s[k] + b1s[k];
                av[kk][j] = (short)f2bf(v);
            }
        }
    }
    floatx4 acc[4];
    #pragma unroll
    for (int nt = 0; nt < 4; ++nt) acc[nt] = (floatx4){0.f, 0.f, 0.f, 0.f};
    #pragma unroll
    for (int nt = 0; nt < 4; ++nt) {
        #pragma unroll
        for (int kk = 0; kk < 8; ++kk) {
            short8 bfr = *(const short8*)(Wvf + ((size_t)(((wave * 4 + nt) * 8 + kk) * 64) + lane) * 8);
            acc[nt] = __builtin_amdgcn_mfma_f32_16x16x32_bf16(av[kk], bfr, acc[nt], 0, 0, 0);
        }
    }
    #pragma unroll
    for (int nt = 0; nt < 4; ++nt) {
        int col = (wave * 4 + nt) * 16 + lr;
        float bb = bvs[col];
        #pragma unroll
        for (int reg = 0; reg < 4; ++reg) {
            int row = quad * 4 + reg;
            vall[(t0 + row) * DM + col] = acc[nt][reg] + bb;
        }
    }
}

// ---------------------------------------------------------------------------
// Kernel B: attn — R7/R8 structure verbatim (32-lane selection, register
// topidx, barrier-free softmax/PV) + T5 s_setprio around MFMA clusters
// (scheduler hint only; 4 independent blocks/CU at different phases).
// ---------------------------------------------------------------------------
__global__ __launch_bounds__(256, 4) void attn_kernel(
    const float* __restrict__ x,
    const float* __restrict__ qn_g, const float* __restrict__ kn_g,
    const unsigned short* __restrict__ knTh, const unsigned short* __restrict__ knTl,
    const float* __restrict__ knsq_g,
    const float* __restrict__ vall,
    const unsigned short* __restrict__ Wof, const float* __restrict__ bo,
    const float* __restrict__ rw, float* __restrict__ out)
{
    __shared__ __align__(16) float s_ld[16 * 512];      // exactly 32KB
    float* attn_s = s_ld;            // 16*128 floats
    float* o8     = s_ld + 2048;     // 16*260 floats (stride 260: conflict-free)

    const int tid = threadIdx.x;
    const int lane = tid & 63, wave = tid >> 6;
    const int quad = lane >> 4, lr = lane & 15;
    const int sg = lane >> 5, sl = lane & 31;     // 32-lane subgroup
    const int sgid = wave * 2 + sg;               // 0..7
    const int b = blockIdx.x & 7;
    const int chunk = blockIdx.x >> 3;            // 0..127
    const size_t tq0 = (size_t)b * SEQ + (size_t)chunk * 16;
    const size_t rowb = (size_t)b * SEQ;

    half8 a_hi[4], a_lo[4];
    {
        const float* qrow = qn_g + (tq0 + lr) * DQK + quad * 8;
        #pragma unroll
        for (int kk = 0; kk < 4; ++kk) {
            float4 fa = *(const float4*)(qrow + kk * 32);
            float4 fb = *(const float4*)(qrow + kk * 32 + 4);
            float vv[8] = {fa.x, fa.y, fa.z, fa.w, fb.x, fb.y, fb.z, fb.w};
            #pragma unroll
            for (int j = 0; j < 8; ++j) {
                float v = vv[j];
                _Float16 h = (_Float16)v;
                a_hi[kk][j] = h;
                a_lo[kk][j] = (_Float16)((v - (float)h) * 4096.f);
            }
        }
    }

    const unsigned short* bh = knTh + (size_t)b * 262144;
    const unsigned short* bl = knTl + (size_t)b * 262144;
    const float* ksqb = knsq_g + rowb;

    ull c0[2], c1[2];          // candidate regs: lane sl holds ranks sl, sl+32

    for (int q4 = 0; q4 < 4; ++q4) {
        if (q4) __syncthreads();

        for (int t = 0; t < 8; ++t) {
            const int tile = q4 * 32 + wave * 8 + t;
            const unsigned short* ph = bh + (size_t)tile * 2048 + lane * 8;
            const unsigned short* pl = bl + (size_t)tile * 2048 + lane * 8;
            floatx4 am  = (floatx4){0.f, 0.f, 0.f, 0.f};
            floatx4 ax1 = (floatx4){0.f, 0.f, 0.f, 0.f};
            floatx4 ax2 = (floatx4){0.f, 0.f, 0.f, 0.f};
            __builtin_amdgcn_s_setprio(1);
            #pragma unroll
            for (int kk = 0; kk < 4; ++kk) {
                half8 bhf = *(const half8*)(ph + kk * 512);
                half8 blf = *(const half8*)(pl + kk * 512);
                am  = __builtin_amdgcn_mfma_f32_16x16x32_f16(a_hi[kk], bhf, am,  0, 0, 0);
                ax1 = __builtin_amdgcn_mfma_f32_16x16x32_f16(a_hi[kk], blf, ax1, 0, 0, 0);
                ax2 = __builtin_amdgcn_mfma_f32_16x16x32_f16(a_lo[kk], bhf, ax2, 0, 0, 0);
            }
            __builtin_amdgcn_s_setprio(0);
            const int keyloc = (wave * 8 + t) * 16 + lr;
            const float kq = ksqb[q4 * 512 + keyloc];
            #pragma unroll
            for (int r = 0; r < 4; ++r) {
                s_ld[(quad * 4 + r) * 512 + keyloc] =
                    2.f * (am[r] + (ax1[r] + ax2[r]) * (1.f / 4096.f)) - kq;
            }
        }
        __syncthreads();

        #pragma unroll
        for (int qi = 0; qi < 2; ++qi) {
            const int q = sgid + 8 * qi;
            const float* srow = &s_ld[q * 512 + sl];
            float f0 = -INFINITY, f1 = -INFINITY;
            int   i0 = 0, i1 = 0;
            #pragma unroll
            for (int i = 0; i < 16; ++i) {
                float f = srow[32 * i];
                int gidx = q4 * 512 + sl + 32 * i;
                bool a  = f > f0;
                bool bb = f > f1;
                f1 = a ? f0 : (bb ? f    : f1);
                i1 = a ? i0 : (bb ? gidx : i1);
                f0 = a ? f    : f0;
                i0 = a ? gidx : i0;
            }
            ull k2v = mkkey(f1, i1);
            ull cur = mkkey(f0, i0);
            int cnt = 0;
            for (int r = 0; r < NK; ++r) {
                ull w = cur;
                #pragma unroll
                for (int m = 1; m < 32; m <<= 1) {
                    ull o = shfl_xor_u64(w, m);
                    if (o > w) w = o;
                }
                const int slot = q4 * 16 + r;
                if (sl == slot)      c0[qi] = w;
                if (sl == slot - 32) c1[qi] = w;
                if (cur == w) {
                    ++cnt;
                    if (cnt == 1) cur = k2v;
                    else {
                        ull best = 0;
                        #pragma unroll
                        for (int i = 0; i < 16; ++i) {
                            float f = srow[32 * i];
                            ull k = mkkey(f, q4 * 512 + sl + 32 * i);
                            if (k < w && k > best) best = k;
                        }
                        cur = best;
                    }
                }
            }
        }
    }
    __syncthreads();

    int tidx[2] = {0, 0};
    #pragma unroll
    for (int qi = 0; qi < 2; ++qi) {
        ull ca = c0[qi], cb = c1[qi];
        ull hi = ca > cb ? ca : cb;
        ull lo = ca > cb ? cb : ca;
        ull cur = hi;
        int cnt = 0;
        for (int r = 0; r < NK; ++r) {
            ull w = cur;
            #pragma unroll
            for (int m = 1; m < 32; m <<= 1) {
                ull o = shfl_xor_u64(w, m);
                if (o > w) w = o;
            }
            if (sl == r) tidx[qi] = 2047 - (int)(unsigned int)(w & 0xFFFFFFFFull);
            if (cur == w) { ++cnt; cur = (cnt == 1) ? lo : 0ull; }
        }
    }

    #pragma unroll
    for (int qq = 0; qq < 4; ++qq) {
        const int sgq = qq & 1;
        const int qiq = qq >> 1;
        const int q   = wave * 2 + sgq + 8 * qiq;
        const int srcb = sgq * 32;
        const int h = lane >> 3;
        const int k1 = lane & 7, k2 = 8 + (lane & 7);
        const int i1 = __shfl(tidx[qiq], srcb + k1);
        const int i2 = __shfl(tidx[qiq], srcb + k2);
        const float* qrow = qn_g + (tq0 + q) * DQK + h * 16;
        const float* kr1 = kn_g + (rowb + i1) * DQK + h * 16;
        const float* kr2 = kn_g + (rowb + i2) * DQK + h * 16;
        float lg1 = 0.f, lg2 = 0.f;
        #pragma unroll
        for (int d = 0; d < 16; d += 4) {
            float4 qv = *(const float4*)&qrow[d];
            float4 a1 = *(const float4*)&kr1[d];
            float4 a2 = *(const float4*)&kr2[d];
            lg1 = fmaf(qv.x, a1.x, lg1); lg1 = fmaf(qv.y, a1.y, lg1);
            lg1 = fmaf(qv.z, a1.z, lg1); lg1 = fmaf(qv.w, a1.w, lg1);
            lg2 = fmaf(qv.x, a2.x, lg2); lg2 = fmaf(qv.y, a2.y, lg2);
            lg2 = fmaf(qv.z, a2.z, lg2); lg2 = fmaf(qv.w, a2.w, lg2);
        }
        lg1 *= 0.25f; lg2 *= 0.25f;
        float mx = fmaxf(lg1, lg2);
        #pragma unroll
        for (int m = 1; m < 8; m <<= 1) mx = fmaxf(mx, __shfl_xor(mx, m));
        float e1 = expf(lg1 - mx), e2 = expf(lg2 - mx);
        float ssum = e1 + e2;
        #pragma unroll
        for (int m = 1; m < 8; m <<= 1) ssum += __shfl_xor(ssum, m);
        attn_s[q * 128 + h * 16 + k1] = e1 / ssum;
        attn_s[q * 128 + h * 16 + k2] = e2 / ssum;
        // within-wave LDS RAW: ordered by lgkmcnt, no barrier needed

        float o[4] = {0.f, 0.f, 0.f, 0.f};
        for (int k = 0; k < NK; ++k) {
            const int ik = __shfl(tidx[qiq], srcb + k);
            const float* vr = vall + (rowb + ik) * DM;
            #pragma unroll
            for (int j = 0; j < 4; ++j) {
                int d = lane + 64 * j;
                o[j] = fmaf(attn_s[q * 128 + (d >> 5) * 16 + k], vr[d], o[j]);
            }
        }
        #pragma unroll
        for (int j = 0; j < 4; ++j) o8[q * 260 + lane + 64 * j] = o[j];
    }
    __syncthreads();    // o8 is read cross-wave in the Wo phase

    {
        short8 ao[8];
        #pragma unroll
        for (int kk = 0; kk < 8; ++kk) {
            #pragma unroll
            for (int j = 0; j < 8; ++j) {
                int k = kk * 32 + quad * 8 + j;
                ao[kk][j] = (short)f2bf(o8[lr * 260 + k]);
            }
        }
        floatx4 aw[4];
        #pragma unroll
        for (int nt = 0; nt < 4; ++nt) aw[nt] = (floatx4){0.f, 0.f, 0.f, 0.f};
        __builtin_amdgcn_s_setprio(1);
        #pragma unroll
        for (int nt = 0; nt < 4; ++nt) {
            #pragma unroll
            for (int kk = 0; kk < 8; ++kk) {
                short8 bofr = *(const short8*)(Wof + ((size_t)(((wave * 4 + nt) * 8 + kk) * 64) + lane) * 8);
                aw[nt] = __builtin_amdgcn_mfma_f32_16x16x32_bf16(ao[kk], bofr, aw[nt], 0, 0, 0);
            }
        }
        __builtin_amdgcn_s_setprio(0);
        float rwv = rw[0];
        #pragma unroll
        for (int nt = 0; nt < 4; ++nt) {
            int col = (wave * 4 + nt) * 16 + lr;
            float bov = bo[col];
            #pragma unroll
            for (int reg = 0; reg < 4; ++reg) {
                int row = quad * 4 + reg;
                size_t t = tq0 + row;
                out[t * DM + col] = x[t * DM + col] + (aw[nt][reg] + bov) * rwv;
            }
        }
    }
}

// ---------------------------------------------------------------------------
// Kernel C: FFN — 32 tokens/block, 512 threads, LDS overlay (R8 verbatim).
// ---------------------------------------------------------------------------
__global__ __launch_bounds__(512, 4) void ffn_kernel(
    float* __restrict__ io,
    const float* __restrict__ gf, const float* __restrict__ bf,
    const unsigned short* __restrict__ W1f, const float* __restrict__ b1f,
    const unsigned short* __restrict__ W2f, const float* __restrict__ b2f,
    const float* __restrict__ rw)
{
    __shared__ __align__(16) char pool[66048];
    __shared__ float gfs[256], bfs[256], b2s[256], b1s[1024];
    __shared__ float stat_m[32], stat_r[32];

    float (*xs)[260] = (float(*)[260])pool;                                  // 33280 B
    unsigned short (*Af)[8 * 64 * 8] = (unsigned short(*)[8 * 64 * 8])(pool + 33280); // 16384 B
    unsigned short (*G)[1032] = (unsigned short(*)[1032])pool;               // 66048 B (overlay)

    const int tid = threadIdx.x;
    const int lane = tid & 63, wave = tid >> 6;      // 8 waves
    const int quad = lane >> 4, lr = lane & 15;
    const size_t t0 = (size_t)blockIdx.x * 32;

    for (int i = tid; i < 32 * 256; i += 512) xs[i >> 8][i & 255] = io[t0 * DM + i];
    if (tid < 256) { gfs[tid] = gf[tid]; bfs[tid] = bf[tid]; b2s[tid] = b2f[tid]; }
    for (int i = tid; i < 1024; i += 512) b1s[i] = b1f[i];
    __syncthreads();

    {
        int tok = tid >> 4, l = tid & 15;
        float s = 0.f, s2 = 0.f;
        #pragma unroll
        for (int i = 0; i < 16; ++i) {
            float v = xs[tok][l + 16 * i];
            s += v; s2 += v * v;
        }
        #pragma unroll
        for (int m = 1; m < 16; m <<= 1) { s += __shfl_xor(s, m); s2 += __shfl_xor(s2, m); }
        if (l == 0) {
            float mean = s * (1.f / 256.f);
            float var  = s2 * (1.f / 256.f) - mean * mean;
            stat_m[tok] = mean;
            stat_r[tok] = rsqrtf(var + 1e-5f);
        }
    }
    __syncthreads();

    // A-fragments: row-tile rt = wave>>2, kk = (wave&3), (wave&3)+4
    {
        const int rt = wave >> 2;
        for (int kk = wave & 3; kk < 8; kk += 4) {
            int m = rt * 16 + lr, k0 = kk * 32 + quad * 8;
            float mm = stat_m[m], rr = stat_r[m];
            unsigned int pk[4];
            #pragma unroll
            for (int jj = 0; jj < 4; ++jj) {
                int ka = k0 + 2 * jj, kb = ka + 1;
                float v0 = (xs[m][ka] - mm) * rr * gfs[ka] + bfs[ka];
                float v1 = (xs[m][kb] - mm) * rr * gfs[kb] + bfs[kb];
                pk[jj] = (unsigned int)f2bf(v0) | ((unsigned int)f2bf(v1) << 16);
            }
            *(uint4*)&Af[rt][(kk * 64 + lane) * 8] = make_uint4(pk[0], pk[1], pk[2], pk[3]);
        }
    }
    __syncthreads();

    short8 afr[2][8];
    #pragma unroll
    for (int rt = 0; rt < 2; ++rt)
        #pragma unroll
        for (int kk = 0; kk < 8; ++kk)
            afr[rt][kk] = *(const short8*)&Af[rt][(kk * 64 + lane) * 8];
    __syncthreads();    // all xs/Af reads done before G overlays the pool

    // GEMM1: wave owns col-tiles (wave*8+nt), nt=0..7; B shared across 2 row-tiles
    for (int nt = 0; nt < 8; ++nt) {
        floatx4 acc0 = (floatx4){0.f, 0.f, 0.f, 0.f};
        floatx4 acc1 = (floatx4){0.f, 0.f, 0.f, 0.f};
        const int ntg = wave * 8 + nt;
        #pragma unroll
        for (int kk = 0; kk < 8; ++kk) {
            short8 bfr = *(const short8*)(W1f + (size_t)((ntg * 8 + kk) * 64 + lane) * 8);
            acc0 = __builtin_amdgcn_mfma_f32_16x16x32_bf16(afr[0][kk], bfr, acc0, 0, 0, 0);
            acc1 = __builtin_amdgcn_mfma_f32_16x16x32_bf16(afr[1][kk], bfr, acc1, 0, 0, 0);
        }
        const int n = ntg * 16 + lr;
        const float bb = b1s[n];
        #pragma unroll
        for (int reg = 0; reg < 4; ++reg) {
            int row = quad * 4 + reg;
            G[row][n]      = f2bf(gelu_fast(acc0[reg] + bb));
            G[row + 16][n] = f2bf(gelu_fast(acc1[reg] + bb));
        }
    }
    __syncthreads();

    // GEMM2: wave owns col-tiles (wave*2+nt2), nt2=0..1; B shared across rows
    floatx4 acc2[2][2];
    #pragma unroll
    for (int nt2 = 0; nt2 < 2; ++nt2)
        #pragma unroll
        for (int rt = 0; rt < 2; ++rt)
            acc2[nt2][rt] = (floatx4){0.f, 0.f, 0.f, 0.f};

    for (int kk2 = 0; kk2 < 32; ++kk2) {
        short8 a20 = *(const short8*)&G[lr][kk2 * 32 + quad * 8];
        short8 a21 = *(const short8*)&G[16 + lr][kk2 * 32 + quad * 8];
        #pragma unroll
        for (int nt2 = 0; nt2 < 2; ++nt2) {
            short8 b2 = *(const short8*)(W2f + (size_t)((((wave * 2 + nt2) * 32 + kk2) * 64 + lane) * 8));
            acc2[nt2][0] = __builtin_amdgcn_mfma_f32_16x16x32_bf16(a20, b2, acc2[nt2][0], 0, 0, 0);
            acc2[nt2][1] = __builtin_amdgcn_mfma_f32_16x16x32_bf16(a21, b2, acc2[nt2][1], 0, 0, 0);
        }
    }

    float rwv = rw[0];
    #pragma unroll
    for (int nt2 = 0; nt2 < 2; ++nt2) {
        int col = (wave * 2 + nt2) * 16 + lr;
        float bb = b2s[col];
        #pragma unroll
        for (int rt = 0; rt < 2; ++rt) {
            #pragma unroll
            for (int reg = 0; reg < 4; ++reg) {
                int row = rt * 16 + quad * 4 + reg;
                float o = acc2[nt2][rt][reg] + bb;
                size_t idx = (t0 + row) * DM + col;
                io[idx] = io[idx] + o * rwv;   // fresh re-read = original value
            }
        }
    }
}

// ---------------------------------------------------------------------------
extern "C" void kernel_launch(void* const* d_in, const int* in_sizes, int n_in,
                              void* d_out, int out_size, void* d_ws, size_t ws_size,
                              hipStream_t stream)
{
    const float* x   = (const float*)d_in[0];
    const float* Wq  = (const float*)d_in[1];
    const float* bq  = (const float*)d_in[2];
    const float* Wk  = (const float*)d_in[3];
    const float* bk  = (const float*)d_in[4];
    const float* Wv  = (const float*)d_in[5];
    const float* bv  = (const float*)d_in[6];
    const float* Wo  = (const float*)d_in[7];
    const float* bo  = (const float*)d_in[8];
    const float* g1  = (const float*)d_in[9];
    const float* b1  = (const float*)d_in[10];
    const float* gf  = (const float*)d_in[11];
    const float* bf  = (const float*)d_in[12];
    const float* W1  = (const float*)d_in[13];
    const float* b1f = (const float*)d_in[14];
    const float* W2  = (const float*)d_in[15];
    const float* b2f = (const float*)d_in[16];
    const float* rw  = (const float*)d_in[17];
    float* out = (float*)d_out;

    // workspace (~43.3 MB): qn | kn | knTh/knTl | vall | knsq | W1f | W2f | Wvf | Wof
    float* ws   = (float*)d_ws;
    float* qn   = ws;                          // 2,097,152 floats
    float* kn   = ws + 2097152;                // 2,097,152
    unsigned short* knTh = (unsigned short*)(ws + 4194304);  // 2,097,152 shorts (4MB)
    unsigned short* knTl = knTh + 2097152;                   // 2,097,152 shorts (4MB)
    float* vall = ws + 6291456;                // 4,194,304
    float* knsq = ws + 10485760;               // 16,384
    unsigned short* W1f = (unsigned short*)(ws + 10502144);   // 262,144 shorts
    unsigned short* W2f = W1f + 262144;                       // 262,144
    unsigned short* Wvf = W2f + 262144;                       // 65,536
    unsigned short* Wof = Wvf + 65536;                        // 65,536

    conv_kernel<<<320, 256, 0, stream>>>(W1, W2, Wv, Wo, W1f, W2f, Wvf, Wof);
    proj_qk_kernel<<<BATCH * SEQ / 8, 256, 0, stream>>>(x, Wq, bq, Wk, bk,
                                                        qn, kn, knTh, knTl, knsq);
    proj_v_kernel<<<BATCH * SEQ / 16, 256, 0, stream>>>(x, bv, g1, b1, Wvf, vall);
    attn_kernel<<<BATCH * SEQ / 16, 256, 0, stream>>>(x, qn, kn, knTh, knTl, knsq, vall,
                                                      Wof, bo, rw, out);
    ffn_kernel<<<BATCH * SEQ / 32, 512, 0, stream>>>(out, gf, bf, W1f, b1f, W2f, b2f, rw);
}

// Round 12
// 340.565 us; speedup vs baseline: 1.2268x; 1.0185x over previous
//
#include <hip/hip_runtime.h>
#include <math.h>

#define BATCH 8
#define SEQ   2048
#define DM    256
#define DQK   128
#define NHEADS 8
#define NK    16
#define DFF   1024

typedef __attribute__((ext_vector_type(8))) short short8;
typedef __attribute__((ext_vector_type(8))) _Float16 half8;
typedef __attribute__((ext_vector_type(4))) float floatx4;
typedef unsigned long long ull;

__device__ __forceinline__ unsigned short f2bf(float f) {
    unsigned int u = __float_as_uint(f);
    u += 0x7fffu + ((u >> 16) & 1u);          // round-to-nearest-even
    return (unsigned short)(u >> 16);
}

__device__ __forceinline__ float gelu_fast(float h) {
    float y = 0.7978845608028654f * (h + 0.044715f * h * h * h);
    float e = __expf(2.f * y);
    float t = 1.f - 2.f / (e + 1.f);
    return 0.5f * h * (1.f + t);
}

// composite sort key: primary score desc, secondary idx asc. Unique per idx.
__device__ __forceinline__ ull mkkey(float f, int gidx) {
    unsigned int u = __float_as_uint(f);
    u ^= (unsigned int)((int)u >> 31) | 0x80000000u;   // sortable float
    return ((ull)u << 32) | (unsigned int)(2047 - gidx);
}

__device__ __forceinline__ ull shfl_xor_u64(ull v, int m) {
    unsigned int lo = (unsigned int)v, hi = (unsigned int)(v >> 32);
    lo = __shfl_xor(lo, m);
    hi = __shfl_xor(hi, m);
    return ((ull)hi << 32) | lo;
}

// ---------------------------------------------------------------------------
// Kernel W: repack W1/W2/Wv/Wo fp32 -> bf16 MFMA B-fragment order (R8 verbatim).
// ---------------------------------------------------------------------------
__global__ __launch_bounds__(256) void conv_kernel(
    const float* __restrict__ W1, const float* __restrict__ W2,
    const float* __restrict__ Wv, const float* __restrict__ Wo,
    unsigned short* __restrict__ W1f, unsigned short* __restrict__ W2f,
    unsigned short* __restrict__ Wvf, unsigned short* __restrict__ Wof)
{
    int g = blockIdx.x * 256 + threadIdx.x;
    const float* W; unsigned short* O; int e, stride;
    if (g < 32768)      { W = W1; O = W1f; e = g;         stride = DFF; }
    else if (g < 65536) { W = W2; O = W2f; e = g - 32768; stride = DM;  }
    else if (g < 73728) { W = Wv; O = Wvf; e = g - 65536; stride = DM;  }
    else                { W = Wo; O = Wof; e = g - 73728; stride = DM;  }
    int lane = e & 63;
    int kk, nt;
    if (g < 32768)      { kk = (e >> 6) & 7;  nt = e >> 9;  }
    else if (g < 65536) { kk = (e >> 6) & 31; nt = e >> 11; }
    else                { kk = (e >> 6) & 7;  nt = e >> 9;  }
    int n = nt * 16 + (lane & 15);
    int k0 = kk * 32 + (lane >> 4) * 8;
    unsigned int pk[4];
    #pragma unroll
    for (int jj = 0; jj < 4; ++jj) {
        unsigned short lo = f2bf(W[(size_t)(k0 + 2 * jj) * stride + n]);
        unsigned short hi = f2bf(W[(size_t)(k0 + 2 * jj + 1) * stride + n]);
        pk[jj] = (unsigned int)lo | ((unsigned int)hi << 16);
    }
    *(uint4*)(O + (size_t)e * 8) = make_uint4(pk[0], pk[1], pk[2], pk[3]);
}

// ---------------------------------------------------------------------------
// Kernel A1: q/k projections — R8 verbatim (coalesced scalar weight loads;
// direct wave-uniform global x reads). Bit-identical fp32 chain.
// ---------------------------------------------------------------------------
__global__ __launch_bounds__(256) void proj_qk_kernel(
    const float* __restrict__ x,
    const float* __restrict__ Wq, const float* __restrict__ bq,
    const float* __restrict__ Wk, const float* __restrict__ bk,
    float* __restrict__ qn, float* __restrict__ kn,
    unsigned short* __restrict__ knTh, unsigned short* __restrict__ knTl,
    float* __restrict__ knsq)
{
    __shared__ __align__(16) float ks[8 * 128];
    __shared__ float nred[8][2], kred[8][2], k2red[8][2];

    const int tid = threadIdx.x;
    const int b = blockIdx.x & 7;
    const int chunk = blockIdx.x >> 3;
    const size_t t0 = (size_t)b * SEQ + (size_t)chunk * 8;

    {
        const int col = tid & 127, half = tid >> 7;
        const int half_u = __builtin_amdgcn_readfirstlane(half);
        const float* xrow[4];
        #pragma unroll
        for (int t = 0; t < 4; ++t)
            xrow[t] = x + (t0 + (size_t)(half_u * 4 + t)) * DM;

        float qa[4] = {0.f, 0.f, 0.f, 0.f}, ka[4] = {0.f, 0.f, 0.f, 0.f};
        for (int d = 0; d < 256; d += 4) {
            float4 xv[4];
            #pragma unroll
            for (int t = 0; t < 4; ++t) xv[t] = *(const float4*)(xrow[t] + d);
            #pragma unroll
            for (int dd = 0; dd < 4; ++dd) {
                float wq = Wq[(d + dd) * DQK + col];
                float wk = Wk[(d + dd) * DQK + col];
                #pragma unroll
                for (int t = 0; t < 4; ++t) {
                    float xval = (dd == 0) ? xv[t].x : (dd == 1) ? xv[t].y
                               : (dd == 2) ? xv[t].z : xv[t].w;
                    qa[t] = fmaf(xval, wq, qa[t]);
                    ka[t] = fmaf(xval, wk, ka[t]);
                }
            }
        }
        #pragma unroll
        for (int t = 0; t < 4; ++t) { qa[t] += bq[col]; ka[t] += bk[col]; }

        const int sub = (tid >> 6) & 1;
        #pragma unroll
        for (int t = 0; t < 4; ++t) {
            float sq = qa[t] * qa[t], sk = ka[t] * ka[t];
            #pragma unroll
            for (int m = 1; m < 64; m <<= 1) { sq += __shfl_xor(sq, m); sk += __shfl_xor(sk, m); }
            if ((tid & 63) == 0) { nred[half * 4 + t][sub] = sq; kred[half * 4 + t][sub] = sk; }
        }
        __syncthreads();
        float kvv[4];
        #pragma unroll
        for (int t = 0; t < 4; ++t) {
            int tok = half * 4 + t;
            float nq = sqrtf(nred[tok][0] + nred[tok][1]);
            float nk = sqrtf(kred[tok][0] + kred[tok][1]);
            float qv = qa[t] / fmaxf(nq, 1e-12f);
            float kv = ka[t] / fmaxf(nk, 1e-12f);
            qn[(t0 + tok) * DQK + col] = qv;
            kn[(t0 + tok) * DQK + col] = kv;
            ks[tok * 128 + col] = kv;
            kvv[t] = kv;
        }
        #pragma unroll
        for (int t = 0; t < 4; ++t) {
            float s2 = kvv[t] * kvv[t];
            #pragma unroll
            for (int m = 1; m < 64; m <<= 1) s2 += __shfl_xor(s2, m);
            if ((tid & 63) == 0) k2red[half * 4 + t][sub] = s2;
        }
        __syncthreads();
        if (tid < 8) knsq[t0 + tid] = k2red[tid][0] + k2red[tid][1];
    }

    // --- K^T -> fp16 hi/lo B-fragments ---
    {
        const int e   = tid & 127;
        const int sel = tid >> 7;           // 0 = hi, 1 = lo(*4096)
        const int key = e & 7;
        const int kq  = e >> 3;             // kk*4 + qd
        const int kk  = kq >> 2, qd = kq & 3;
        const int nt  = chunk >> 1;
        const int n   = ((chunk & 1) << 3) + key;
        const float* src = &ks[key * 128 + kk * 32 + qd * 8];
        unsigned int pk[4];
        #pragma unroll
        for (int jj = 0; jj < 4; ++jj) {
            float v0 = src[2 * jj], v1 = src[2 * jj + 1];
            _Float16 h0 = (_Float16)v0, h1 = (_Float16)v1;
            unsigned short u0, u1;
            if (sel == 0) {
                u0 = __builtin_bit_cast(unsigned short, h0);
                u1 = __builtin_bit_cast(unsigned short, h1);
            } else {
                _Float16 l0 = (_Float16)((v0 - (float)h0) * 4096.f);
                _Float16 l1 = (_Float16)((v1 - (float)h1) * 4096.f);
                u0 = __builtin_bit_cast(unsigned short, l0);
                u1 = __builtin_bit_cast(unsigned short, l1);
            }
            pk[jj] = (unsigned int)u0 | ((unsigned int)u1 << 16);
        }
        unsigned short* dst = (sel ? knTl : knTh)
            + (size_t)b * 262144
            + (size_t)((nt * 4 + kk) * 64 + qd * 16 + n) * 8;
        *(uint4*)dst = make_uint4(pk[0], pk[1], pk[2], pk[3]);
    }
}

// ---------------------------------------------------------------------------
// Kernel A2: v projection via bf16 MFMA (unchanged — passing).
// ---------------------------------------------------------------------------
__global__ __launch_bounds__(256) void proj_v_kernel(
    const float* __restrict__ x,
    const float* __restrict__ bv, const float* __restrict__ g1,
    const float* __restrict__ b1,
    const unsigned short* __restrict__ Wvf, float* __restrict__ vall)
{
    __shared__ __align__(16) float xs[16][260];
    __shared__ float stat_m[16], stat_r[16];
    __shared__ float bvs[256], g1s[256], b1s[256];

    const int tid = threadIdx.x;
    const int lane = tid & 63, wave = tid >> 6;
    const int quad = lane >> 4, lr = lane & 15;
    const size_t t0 = (size_t)blockIdx.x * 16;

    for (int i = tid; i < 16 * 256; i += 256) xs[i >> 8][i & 255] = x[t0 * DM + i];
    bvs[tid] = bv[tid]; g1s[tid] = g1[tid]; b1s[tid] = b1[tid];
    __syncthreads();

    {
        int tok = tid >> 4, l = tid & 15;
        float s = 0.f, s2 = 0.f;
        #pragma unroll
        for (int i = 0; i < 16; ++i) {
            float v = xs[tok][l + 16 * i];
            s += v; s2 += v * v;
        }
        #pragma unroll
        for (int m = 1; m < 16; m <<= 1) { s += __shfl_xor(s, m); s2 += __shfl_xor(s2, m); }
        if (l == 0) {
            float mean = s * (1.f / 256.f);
            float var  = s2 * (1.f / 256.f) - mean * mean;
            stat_m[tok] = mean;
            stat_r[tok] = rsqrtf(var + 1e-5f);
        }
    }
    __syncthreads();

    short8 av[8];
    {
        float mm = stat_m[lr], rr = stat_r[lr];
        #pragma unroll
        for (int kk = 0; kk < 8; ++kk) {
            #pragma unroll
            for (int j = 0; j < 8; ++j) {
                int k = kk * 32 + quad * 8 + j;
                float v = (xs[lr][k] - mm) * rr * g1s[k] + b1s[k];
                av[kk][j] = (short)f2bf(v);
            }
        }
    }
    floatx4 acc[4];
    #pragma unroll
    for (int nt = 0; nt < 4; ++nt) acc[nt] = (floatx4){0.f, 0.f, 0.f, 0.f};
    #pragma unroll
    for (int nt = 0; nt < 4; ++nt) {
        #pragma unroll
        for (int kk = 0; kk < 8; ++kk) {
            short8 bfr = *(const short8*)(Wvf + ((size_t)(((wave * 4 + nt) * 8 + kk) * 64) + lane) * 8);
            acc[nt] = __builtin_amdgcn_mfma_f32_16x16x32_bf16(av[kk], bfr, acc[nt], 0, 0, 0);
        }
    }
    #pragma unroll
    for (int nt = 0; nt < 4; ++nt) {
        int col = (wave * 4 + nt) * 16 + lr;
        float bb = bvs[col];
        #pragma unroll
        for (int reg = 0; reg < 4; ++reg) {
            int row = quad * 4 + reg;
            vall[(t0 + row) * DM + col] = acc[nt][reg] + bb;
        }
    }
}

// ---------------------------------------------------------------------------
// Kernel B: attn — R8 verbatim (32-lane selection, register topidx,
// barrier-free softmax/PV, no setprio). Measured 161us.
// ---------------------------------------------------------------------------
__global__ __launch_bounds__(256, 4) void attn_kernel(
    const float* __restrict__ x,
    const float* __restrict__ qn_g, const float* __restrict__ kn_g,
    const unsigned short* __restrict__ knTh, const unsigned short* __restrict__ knTl,
    const float* __restrict__ knsq_g,
    const float* __restrict__ vall,
    const unsigned short* __restrict__ Wof, const float* __restrict__ bo,
    const float* __restrict__ rw, float* __restrict__ out)
{
    __shared__ __align__(16) float s_ld[16 * 512];      // exactly 32KB
    float* attn_s = s_ld;            // 16*128 floats
    float* o8     = s_ld + 2048;     // 16*260 floats (stride 260: conflict-free)

    const int tid = threadIdx.x;
    const int lane = tid & 63, wave = tid >> 6;
    const int quad = lane >> 4, lr = lane & 15;
    const int sg = lane >> 5, sl = lane & 31;     // 32-lane subgroup
    const int sgid = wave * 2 + sg;               // 0..7
    const int b = blockIdx.x & 7;
    const int chunk = blockIdx.x >> 3;            // 0..127
    const size_t tq0 = (size_t)b * SEQ + (size_t)chunk * 16;
    const size_t rowb = (size_t)b * SEQ;

    half8 a_hi[4], a_lo[4];
    {
        const float* qrow = qn_g + (tq0 + lr) * DQK + quad * 8;
        #pragma unroll
        for (int kk = 0; kk < 4; ++kk) {
            float4 fa = *(const float4*)(qrow + kk * 32);
            float4 fb = *(const float4*)(qrow + kk * 32 + 4);
            float vv[8] = {fa.x, fa.y, fa.z, fa.w, fb.x, fb.y, fb.z, fb.w};
            #pragma unroll
            for (int j = 0; j < 8; ++j) {
                float v = vv[j];
                _Float16 h = (_Float16)v;
                a_hi[kk][j] = h;
                a_lo[kk][j] = (_Float16)((v - (float)h) * 4096.f);
            }
        }
    }

    const unsigned short* bh = knTh + (size_t)b * 262144;
    const unsigned short* bl = knTl + (size_t)b * 262144;
    const float* ksqb = knsq_g + rowb;

    ull c0[2], c1[2];          // candidate regs: lane sl holds ranks sl, sl+32

    for (int q4 = 0; q4 < 4; ++q4) {
        if (q4) __syncthreads();

        for (int t = 0; t < 8; ++t) {
            const int tile = q4 * 32 + wave * 8 + t;
            const unsigned short* ph = bh + (size_t)tile * 2048 + lane * 8;
            const unsigned short* pl = bl + (size_t)tile * 2048 + lane * 8;
            floatx4 am  = (floatx4){0.f, 0.f, 0.f, 0.f};
            floatx4 ax1 = (floatx4){0.f, 0.f, 0.f, 0.f};
            floatx4 ax2 = (floatx4){0.f, 0.f, 0.f, 0.f};
            #pragma unroll
            for (int kk = 0; kk < 4; ++kk) {
                half8 bhf = *(const half8*)(ph + kk * 512);
                half8 blf = *(const half8*)(pl + kk * 512);
                am  = __builtin_amdgcn_mfma_f32_16x16x32_f16(a_hi[kk], bhf, am,  0, 0, 0);
                ax1 = __builtin_amdgcn_mfma_f32_16x16x32_f16(a_hi[kk], blf, ax1, 0, 0, 0);
                ax2 = __builtin_amdgcn_mfma_f32_16x16x32_f16(a_lo[kk], bhf, ax2, 0, 0, 0);
            }
            const int keyloc = (wave * 8 + t) * 16 + lr;
            const float kq = ksqb[q4 * 512 + keyloc];
            #pragma unroll
            for (int r = 0; r < 4; ++r) {
                s_ld[(quad * 4 + r) * 512 + keyloc] =
                    2.f * (am[r] + (ax1[r] + ax2[r]) * (1.f / 4096.f)) - kq;
            }
        }
        __syncthreads();

        #pragma unroll
        for (int qi = 0; qi < 2; ++qi) {
            const int q = sgid + 8 * qi;
            const float* srow = &s_ld[q * 512 + sl];
            float f0 = -INFINITY, f1 = -INFINITY;
            int   i0 = 0, i1 = 0;
            #pragma unroll
            for (int i = 0; i < 16; ++i) {
                float f = srow[32 * i];
                int gidx = q4 * 512 + sl + 32 * i;
                bool a  = f > f0;
                bool bb = f > f1;
                f1 = a ? f0 : (bb ? f    : f1);
                i1 = a ? i0 : (bb ? gidx : i1);
                f0 = a ? f    : f0;
                i0 = a ? gidx : i0;
            }
            ull k2v = mkkey(f1, i1);
            ull cur = mkkey(f0, i0);
            int cnt = 0;
            for (int r = 0; r < NK; ++r) {
                ull w = cur;
                #pragma unroll
                for (int m = 1; m < 32; m <<= 1) {
                    ull o = shfl_xor_u64(w, m);
                    if (o > w) w = o;
                }
                const int slot = q4 * 16 + r;
                if (sl == slot)      c0[qi] = w;
                if (sl == slot - 32) c1[qi] = w;
                if (cur == w) {
                    ++cnt;
                    if (cnt == 1) cur = k2v;
                    else {
                        ull best = 0;
                        #pragma unroll
                        for (int i = 0; i < 16; ++i) {
                            float f = srow[32 * i];
                            ull k = mkkey(f, q4 * 512 + sl + 32 * i);
                            if (k < w && k > best) best = k;
                        }
                        cur = best;
                    }
                }
            }
        }
    }
    __syncthreads();

    int tidx[2] = {0, 0};
    #pragma unroll
    for (int qi = 0; qi < 2; ++qi) {
        ull ca = c0[qi], cb = c1[qi];
        ull hi = ca > cb ? ca : cb;
        ull lo = ca > cb ? cb : ca;
        ull cur = hi;
        int cnt = 0;
        for (int r = 0; r < NK; ++r) {
            ull w = cur;
            #pragma unroll
            for (int m = 1; m < 32; m <<= 1) {
                ull o = shfl_xor_u64(w, m);
                if (o > w) w = o;
            }
            if (sl == r) tidx[qi] = 2047 - (int)(unsigned int)(w & 0xFFFFFFFFull);
            if (cur == w) { ++cnt; cur = (cnt == 1) ? lo : 0ull; }
        }
    }

    #pragma unroll
    for (int qq = 0; qq < 4; ++qq) {
        const int sgq = qq & 1;
        const int qiq = qq >> 1;
        const int q   = wave * 2 + sgq + 8 * qiq;
        const int srcb = sgq * 32;
        const int h = lane >> 3;
        const int k1 = lane & 7, k2 = 8 + (lane & 7);
        const int i1 = __shfl(tidx[qiq], srcb + k1);
        const int i2 = __shfl(tidx[qiq], srcb + k2);
        const float* qrow = qn_g + (tq0 + q) * DQK + h * 16;
        const float* kr1 = kn_g + (rowb + i1) * DQK + h * 16;
        const float* kr2 = kn_g + (rowb + i2) * DQK + h * 16;
        float lg1 = 0.f, lg2 = 0.f;
        #pragma unroll
        for (int d = 0; d < 16; d += 4) {
            float4 qv = *(const float4*)&qrow[d];
            float4 a1 = *(const float4*)&kr1[d];
            float4 a2 = *(const float4*)&kr2[d];
            lg1 = fmaf(qv.x, a1.x, lg1); lg1 = fmaf(qv.y, a1.y, lg1);
            lg1 = fmaf(qv.z, a1.z, lg1); lg1 = fmaf(qv.w, a1.w, lg1);
            lg2 = fmaf(qv.x, a2.x, lg2); lg2 = fmaf(qv.y, a2.y, lg2);
            lg2 = fmaf(qv.z, a2.z, lg2); lg2 = fmaf(qv.w, a2.w, lg2);
        }
        lg1 *= 0.25f; lg2 *= 0.25f;
        float mx = fmaxf(lg1, lg2);
        #pragma unroll
        for (int m = 1; m < 8; m <<= 1) mx = fmaxf(mx, __shfl_xor(mx, m));
        float e1 = expf(lg1 - mx), e2 = expf(lg2 - mx);
        float ssum = e1 + e2;
        #pragma unroll
        for (int m = 1; m < 8; m <<= 1) ssum += __shfl_xor(ssum, m);
        attn_s[q * 128 + h * 16 + k1] = e1 / ssum;
        attn_s[q * 128 + h * 16 + k2] = e2 / ssum;
        // within-wave LDS RAW: ordered by lgkmcnt, no barrier needed

        float o[4] = {0.f, 0.f, 0.f, 0.f};
        for (int k = 0; k < NK; ++k) {
            const int ik = __shfl(tidx[qiq], srcb + k);
            const float* vr = vall + (rowb + ik) * DM;
            #pragma unroll
            for (int j = 0; j < 4; ++j) {
                int d = lane + 64 * j;
                o[j] = fmaf(attn_s[q * 128 + (d >> 5) * 16 + k], vr[d], o[j]);
            }
        }
        #pragma unroll
        for (int j = 0; j < 4; ++j) o8[q * 260 + lane + 64 * j] = o[j];
    }
    __syncthreads();    // o8 is read cross-wave in the Wo phase

    {
        short8 ao[8];
        #pragma unroll
        for (int kk = 0; kk < 8; ++kk) {
            #pragma unroll
            for (int j = 0; j < 8; ++j) {
                int k = kk * 32 + quad * 8 + j;
                ao[kk][j] = (short)f2bf(o8[lr * 260 + k]);
            }
        }
        floatx4 aw[4];
        #pragma unroll
        for (int nt = 0; nt < 4; ++nt) aw[nt] = (floatx4){0.f, 0.f, 0.f, 0.f};
        #pragma unroll
        for (int nt = 0; nt < 4; ++nt) {
            #pragma unroll
            for (int kk = 0; kk < 8; ++kk) {
                short8 bofr = *(const short8*)(Wof + ((size_t)(((wave * 4 + nt) * 8 + kk) * 64) + lane) * 8);
                aw[nt] = __builtin_amdgcn_mfma_f32_16x16x32_bf16(ao[kk], bofr, aw[nt], 0, 0, 0);
            }
        }
        float rwv = rw[0];
        #pragma unroll
        for (int nt = 0; nt < 4; ++nt) {
            int col = (wave * 4 + nt) * 16 + lr;
            float bov = bo[col];
            #pragma unroll
            for (int reg = 0; reg < 4; ++reg) {
                int row = quad * 4 + reg;
                size_t t = tq0 + row;
                out[t * DM + col] = x[t * DM + col] + (aw[nt][reg] + bov) * rwv;
            }
        }
    }
}

// ---------------------------------------------------------------------------
// Kernel C: FFN — 32 tokens/block, 512 threads, LDS overlay (R8 verbatim).
// ---------------------------------------------------------------------------
__global__ __launch_bounds__(512, 4) void ffn_kernel(
    float* __restrict__ io,
    const float* __restrict__ gf, const float* __restrict__ bf,
    const unsigned short* __restrict__ W1f, const float* __restrict__ b1f,
    const unsigned short* __restrict__ W2f, const float* __restrict__ b2f,
    const float* __restrict__ rw)
{
    __shared__ __align__(16) char pool[66048];
    __shared__ float gfs[256], bfs[256], b2s[256], b1s[1024];
    __shared__ float stat_m[32], stat_r[32];

    float (*xs)[260] = (float(*)[260])pool;                                  // 33280 B
    unsigned short (*Af)[8 * 64 * 8] = (unsigned short(*)[8 * 64 * 8])(pool + 33280); // 16384 B
    unsigned short (*G)[1032] = (unsigned short(*)[1032])pool;               // 66048 B (overlay)

    const int tid = threadIdx.x;
    const int lane = tid & 63, wave = tid >> 6;      // 8 waves
    const int quad = lane >> 4, lr = lane & 15;
    const size_t t0 = (size_t)blockIdx.x * 32;

    for (int i = tid; i < 32 * 256; i += 512) xs[i >> 8][i & 255] = io[t0 * DM + i];
    if (tid < 256) { gfs[tid] = gf[tid]; bfs[tid] = bf[tid]; b2s[tid] = b2f[tid]; }
    for (int i = tid; i < 1024; i += 512) b1s[i] = b1f[i];
    __syncthreads();

    {
        int tok = tid >> 4, l = tid & 15;
        float s = 0.f, s2 = 0.f;
        #pragma unroll
        for (int i = 0; i < 16; ++i) {
            float v = xs[tok][l + 16 * i];
            s += v; s2 += v * v;
        }
        #pragma unroll
        for (int m = 1; m < 16; m <<= 1) { s += __shfl_xor(s, m); s2 += __shfl_xor(s2, m); }
        if (l == 0) {
            float mean = s * (1.f / 256.f);
            float var  = s2 * (1.f / 256.f) - mean * mean;
            stat_m[tok] = mean;
            stat_r[tok] = rsqrtf(var + 1e-5f);
        }
    }
    __syncthreads();

    // A-fragments: row-tile rt = wave>>2, kk = (wave&3), (wave&3)+4
    {
        const int rt = wave >> 2;
        for (int kk = wave & 3; kk < 8; kk += 4) {
            int m = rt * 16 + lr, k0 = kk * 32 + quad * 8;
            float mm = stat_m[m], rr = stat_r[m];
            unsigned int pk[4];
            #pragma unroll
            for (int jj = 0; jj < 4; ++jj) {
                int ka = k0 + 2 * jj, kb = ka + 1;
                float v0 = (xs[m][ka] - mm) * rr * gfs[ka] + bfs[ka];
                float v1 = (xs[m][kb] - mm) * rr * gfs[kb] + bfs[kb];
                pk[jj] = (unsigned int)f2bf(v0) | ((unsigned int)f2bf(v1) << 16);
            }
            *(uint4*)&Af[rt][(kk * 64 + lane) * 8] = make_uint4(pk[0], pk[1], pk[2], pk[3]);
        }
    }
    __syncthreads();

    short8 afr[2][8];
    #pragma unroll
    for (int rt = 0; rt < 2; ++rt)
        #pragma unroll
        for (int kk = 0; kk < 8; ++kk)
            afr[rt][kk] = *(const short8*)&Af[rt][(kk * 64 + lane) * 8];
    __syncthreads();    // all xs/Af reads done before G overlays the pool

    // GEMM1: wave owns col-tiles (wave*8+nt), nt=0..7; B shared across 2 row-tiles
    for (int nt = 0; nt < 8; ++nt) {
        floatx4 acc0 = (floatx4){0.f, 0.f, 0.f, 0.f};
        floatx4 acc1 = (floatx4){0.f, 0.f, 0.f, 0.f};
        const int ntg = wave * 8 + nt;
        #pragma unroll
        for (int kk = 0; kk < 8; ++kk) {
            short8 bfr = *(const short8*)(W1f + (size_t)((ntg * 8 + kk) * 64 + lane) * 8);
            acc0 = __builtin_amdgcn_mfma_f32_16x16x32_bf16(afr[0][kk], bfr, acc0, 0, 0, 0);
            acc1 = __builtin_amdgcn_mfma_f32_16x16x32_bf16(afr[1][kk], bfr, acc1, 0, 0, 0);
        }
        const int n = ntg * 16 + lr;
        const float bb = b1s[n];
        #pragma unroll
        for (int reg = 0; reg < 4; ++reg) {
            int row = quad * 4 + reg;
            G[row][n]      = f2bf(gelu_fast(acc0[reg] + bb));
            G[row + 16][n] = f2bf(gelu_fast(acc1[reg] + bb));
        }
    }
    __syncthreads();

    // GEMM2: wave owns col-tiles (wave*2+nt2), nt2=0..1; B shared across rows
    floatx4 acc2[2][2];
    #pragma unroll
    for (int nt2 = 0; nt2 < 2; ++nt2)
        #pragma unroll
        for (int rt = 0; rt < 2; ++rt)
            acc2[nt2][rt] = (floatx4){0.f, 0.f, 0.f, 0.f};

    for (int kk2 = 0; kk2 < 32; ++kk2) {
        short8 a20 = *(const short8*)&G[lr][kk2 * 32 + quad * 8];
        short8 a21 = *(const short8*)&G[16 + lr][kk2 * 32 + quad * 8];
        #pragma unroll
        for (int nt2 = 0; nt2 < 2; ++nt2) {
            short8 b2 = *(const short8*)(W2f + (size_t)((((wave * 2 + nt2) * 32 + kk2) * 64 + lane) * 8));
            acc2[nt2][0] = __builtin_amdgcn_mfma_f32_16x16x32_bf16(a20, b2, acc2[nt2][0], 0, 0, 0);
            acc2[nt2][1] = __builtin_amdgcn_mfma_f32_16x16x32_bf16(a21, b2, acc2[nt2][1], 0, 0, 0);
        }
    }

    float rwv = rw[0];
    #pragma unroll
    for (int nt2 = 0; nt2 < 2; ++nt2) {
        int col = (wave * 2 + nt2) * 16 + lr;
        float bb = b2s[col];
        #pragma unroll
        for (int rt = 0; rt < 2; ++rt) {
            #pragma unroll
            for (int reg = 0; reg < 4; ++reg) {
                int row = rt * 16 + quad * 4 + reg;
                float o = acc2[nt2][rt][reg] + bb;
                size_t idx = (t0 + row) * DM + col;
                io[idx] = io[idx] + o * rwv;   // fresh re-read = original value
            }
        }
    }
}

// ---------------------------------------------------------------------------
extern "C" void kernel_launch(void* const* d_in, const int* in_sizes, int n_in,
                              void* d_out, int out_size, void* d_ws, size_t ws_size,
                              hipStream_t stream)
{
    const float* x   = (const float*)d_in[0];
    const float* Wq  = (const float*)d_in[1];
    const float* bq  = (const float*)d_in[2];
    const float* Wk  = (const float*)d_in[3];
    const float* bk  = (const float*)d_in[4];
    const float* Wv  = (const float*)d_in[5];
    const float* bv  = (const float*)d_in[6];
    const float* Wo  = (const float*)d_in[7];
    const float* bo  = (const float*)d_in[8];
    const float* g1  = (const float*)d_in[9];
    const float* b1  = (const float*)d_in[10];
    const float* gf  = (const float*)d_in[11];
    const float* bf  = (const float*)d_in[12];
    const float* W1  = (const float*)d_in[13];
    const float* b1f = (const float*)d_in[14];
    const float* W2  = (const float*)d_in[15];
    const float* b2f = (const float*)d_in[16];
    const float* rw  = (const float*)d_in[17];
    float* out = (float*)d_out;

    // workspace (~43.3 MB): qn | kn | knTh/knTl | vall | knsq | W1f | W2f | Wvf | Wof
    float* ws   = (float*)d_ws;
    float* qn   = ws;                          // 2,097,152 floats
    float* kn   = ws + 2097152;                // 2,097,152
    unsigned short* knTh = (unsigned short*)(ws + 4194304);  // 2,097,152 shorts (4MB)
    unsigned short* knTl = knTh + 2097152;                   // 2,097,152 shorts (4MB)
    float* vall = ws + 6291456;                // 4,194,304
    float* knsq = ws + 10485760;               // 16,384
    unsigned short* W1f = (unsigned short*)(ws + 10502144);   // 262,144 shorts
    unsigned short* W2f = W1f + 262144;                       // 262,144
    unsigned short* Wvf = W2f + 262144;                       // 65,536
    unsigned short* Wof = Wvf + 65536;                        // 65,536

    conv_kernel<<<320, 256, 0, stream>>>(W1, W2, Wv, Wo, W1f, W2f, Wvf, Wof);
    proj_qk_kernel<<<BATCH * SEQ / 8, 256, 0, stream>>>(x, Wq, bq, Wk, bk,
                                                        qn, kn, knTh, knTl, knsq);
    proj_v_kernel<<<BATCH * SEQ / 16, 256, 0, stream>>>(x, bv, g1, b1, Wvf, vall);
    attn_kernel<<<BATCH * SEQ / 16, 256, 0, stream>>>(x, qn, kn, knTh, knTl, knsq, vall,
                                                      Wof, bo, rw, out);
    ffn_kernel<<<BATCH * SEQ / 32, 512, 0, stream>>>(out, gf, bf, W1f, b1f, W2f, b2f, rw);
}

// Round 13
// 332.407 us; speedup vs baseline: 1.2569x; 1.0245x over previous
//
#include <hip/hip_runtime.h>
#include <math.h>

#define BATCH 8
#define SEQ   2048
#define DM    256
#define DQK   128
#define NHEADS 8
#define NK    16
#define DFF   1024

typedef __attribute__((ext_vector_type(8))) short short8;
typedef __attribute__((ext_vector_type(8))) _Float16 half8;
typedef __attribute__((ext_vector_type(4))) float floatx4;
typedef unsigned long long ull;

__device__ __forceinline__ unsigned short f2bf(float f) {
    unsigned int u = __float_as_uint(f);
    u += 0x7fffu + ((u >> 16) & 1u);          // round-to-nearest-even
    return (unsigned short)(u >> 16);
}

__device__ __forceinline__ float gelu_fast(float h) {
    float y = 0.7978845608028654f * (h + 0.044715f * h * h * h);
    float e = __expf(2.f * y);
    float t = 1.f - 2.f / (e + 1.f);
    return 0.5f * h * (1.f + t);
}

// composite sort key: primary score desc, secondary idx asc. Unique per idx.
__device__ __forceinline__ ull mkkey(float f, int gidx) {
    unsigned int u = __float_as_uint(f);
    u ^= (unsigned int)((int)u >> 31) | 0x80000000u;   // sortable float
    return ((ull)u << 32) | (unsigned int)(2047 - gidx);
}

__device__ __forceinline__ ull shfl_xor_u64(ull v, int m) {
    unsigned int lo = (unsigned int)v, hi = (unsigned int)(v >> 32);
    lo = __shfl_xor(lo, m);
    hi = __shfl_xor(hi, m);
    return ((ull)hi << 32) | lo;
}

// ---------------------------------------------------------------------------
// Kernel W: repack W1/W2/Wv/Wo fp32 -> bf16 MFMA B-fragment order (R8 verbatim).
// ---------------------------------------------------------------------------
__global__ __launch_bounds__(256) void conv_kernel(
    const float* __restrict__ W1, const float* __restrict__ W2,
    const float* __restrict__ Wv, const float* __restrict__ Wo,
    unsigned short* __restrict__ W1f, unsigned short* __restrict__ W2f,
    unsigned short* __restrict__ Wvf, unsigned short* __restrict__ Wof)
{
    int g = blockIdx.x * 256 + threadIdx.x;
    const float* W; unsigned short* O; int e, stride;
    if (g < 32768)      { W = W1; O = W1f; e = g;         stride = DFF; }
    else if (g < 65536) { W = W2; O = W2f; e = g - 32768; stride = DM;  }
    else if (g < 73728) { W = Wv; O = Wvf; e = g - 65536; stride = DM;  }
    else                { W = Wo; O = Wof; e = g - 73728; stride = DM;  }
    int lane = e & 63;
    int kk, nt;
    if (g < 32768)      { kk = (e >> 6) & 7;  nt = e >> 9;  }
    else if (g < 65536) { kk = (e >> 6) & 31; nt = e >> 11; }
    else                { kk = (e >> 6) & 7;  nt = e >> 9;  }
    int n = nt * 16 + (lane & 15);
    int k0 = kk * 32 + (lane >> 4) * 8;
    unsigned int pk[4];
    #pragma unroll
    for (int jj = 0; jj < 4; ++jj) {
        unsigned short lo = f2bf(W[(size_t)(k0 + 2 * jj) * stride + n]);
        unsigned short hi = f2bf(W[(size_t)(k0 + 2 * jj + 1) * stride + n]);
        pk[jj] = (unsigned int)lo | ((unsigned int)hi << 16);
    }
    *(uint4*)(O + (size_t)e * 8) = make_uint4(pk[0], pk[1], pk[2], pk[3]);
}

// ---------------------------------------------------------------------------
// Kernel A1: q/k projections — R8 verbatim. Bit-identical fp32 chain.
// ---------------------------------------------------------------------------
__global__ __launch_bounds__(256) void proj_qk_kernel(
    const float* __restrict__ x,
    const float* __restrict__ Wq, const float* __restrict__ bq,
    const float* __restrict__ Wk, const float* __restrict__ bk,
    float* __restrict__ qn, float* __restrict__ kn,
    unsigned short* __restrict__ knTh, unsigned short* __restrict__ knTl,
    float* __restrict__ knsq)
{
    __shared__ __align__(16) float ks[8 * 128];
    __shared__ float nred[8][2], kred[8][2], k2red[8][2];

    const int tid = threadIdx.x;
    const int b = blockIdx.x & 7;
    const int chunk = blockIdx.x >> 3;
    const size_t t0 = (size_t)b * SEQ + (size_t)chunk * 8;

    {
        const int col = tid & 127, half = tid >> 7;
        const int half_u = __builtin_amdgcn_readfirstlane(half);
        const float* xrow[4];
        #pragma unroll
        for (int t = 0; t < 4; ++t)
            xrow[t] = x + (t0 + (size_t)(half_u * 4 + t)) * DM;

        float qa[4] = {0.f, 0.f, 0.f, 0.f}, ka[4] = {0.f, 0.f, 0.f, 0.f};
        for (int d = 0; d < 256; d += 4) {
            float4 xv[4];
            #pragma unroll
            for (int t = 0; t < 4; ++t) xv[t] = *(const float4*)(xrow[t] + d);
            #pragma unroll
            for (int dd = 0; dd < 4; ++dd) {
                float wq = Wq[(d + dd) * DQK + col];
                float wk = Wk[(d + dd) * DQK + col];
                #pragma unroll
                for (int t = 0; t < 4; ++t) {
                    float xval = (dd == 0) ? xv[t].x : (dd == 1) ? xv[t].y
                               : (dd == 2) ? xv[t].z : xv[t].w;
                    qa[t] = fmaf(xval, wq, qa[t]);
                    ka[t] = fmaf(xval, wk, ka[t]);
                }
            }
        }
        #pragma unroll
        for (int t = 0; t < 4; ++t) { qa[t] += bq[col]; ka[t] += bk[col]; }

        const int sub = (tid >> 6) & 1;
        #pragma unroll
        for (int t = 0; t < 4; ++t) {
            float sq = qa[t] * qa[t], sk = ka[t] * ka[t];
            #pragma unroll
            for (int m = 1; m < 64; m <<= 1) { sq += __shfl_xor(sq, m); sk += __shfl_xor(sk, m); }
            if ((tid & 63) == 0) { nred[half * 4 + t][sub] = sq; kred[half * 4 + t][sub] = sk; }
        }
        __syncthreads();
        float kvv[4];
        #pragma unroll
        for (int t = 0; t < 4; ++t) {
            int tok = half * 4 + t;
            float nq = sqrtf(nred[tok][0] + nred[tok][1]);
            float nk = sqrtf(kred[tok][0] + kred[tok][1]);
            float qv = qa[t] / fmaxf(nq, 1e-12f);
            float kv = ka[t] / fmaxf(nk, 1e-12f);
            qn[(t0 + tok) * DQK + col] = qv;
            kn[(t0 + tok) * DQK + col] = kv;
            ks[tok * 128 + col] = kv;
            kvv[t] = kv;
        }
        #pragma unroll
        for (int t = 0; t < 4; ++t) {
            float s2 = kvv[t] * kvv[t];
            #pragma unroll
            for (int m = 1; m < 64; m <<= 1) s2 += __shfl_xor(s2, m);
            if ((tid & 63) == 0) k2red[half * 4 + t][sub] = s2;
        }
        __syncthreads();
        if (tid < 8) knsq[t0 + tid] = k2red[tid][0] + k2red[tid][1];
    }

    // --- K^T -> fp16 hi/lo B-fragments ---
    {
        const int e   = tid & 127;
        const int sel = tid >> 7;           // 0 = hi, 1 = lo(*4096)
        const int key = e & 7;
        const int kq  = e >> 3;             // kk*4 + qd
        const int kk  = kq >> 2, qd = kq & 3;
        const int nt  = chunk >> 1;
        const int n   = ((chunk & 1) << 3) + key;
        const float* src = &ks[key * 128 + kk * 32 + qd * 8];
        unsigned int pk[4];
        #pragma unroll
        for (int jj = 0; jj < 4; ++jj) {
            float v0 = src[2 * jj], v1 = src[2 * jj + 1];
            _Float16 h0 = (_Float16)v0, h1 = (_Float16)v1;
            unsigned short u0, u1;
            if (sel == 0) {
                u0 = __builtin_bit_cast(unsigned short, h0);
                u1 = __builtin_bit_cast(unsigned short, h1);
            } else {
                _Float16 l0 = (_Float16)((v0 - (float)h0) * 4096.f);
                _Float16 l1 = (_Float16)((v1 - (float)h1) * 4096.f);
                u0 = __builtin_bit_cast(unsigned short, l0);
                u1 = __builtin_bit_cast(unsigned short, l1);
            }
            pk[jj] = (unsigned int)u0 | ((unsigned int)u1 << 16);
        }
        unsigned short* dst = (sel ? knTl : knTh)
            + (size_t)b * 262144
            + (size_t)((nt * 4 + kk) * 64 + qd * 16 + n) * 8;
        *(uint4*)dst = make_uint4(pk[0], pk[1], pk[2], pk[3]);
    }
}

// ---------------------------------------------------------------------------
// Kernel A2: v projection via bf16 MFMA (unchanged — passing).
// ---------------------------------------------------------------------------
__global__ __launch_bounds__(256) void proj_v_kernel(
    const float* __restrict__ x,
    const float* __restrict__ bv, const float* __restrict__ g1,
    const float* __restrict__ b1,
    const unsigned short* __restrict__ Wvf, float* __restrict__ vall)
{
    __shared__ __align__(16) float xs[16][260];
    __shared__ float stat_m[16], stat_r[16];
    __shared__ float bvs[256], g1s[256], b1s[256];

    const int tid = threadIdx.x;
    const int lane = tid & 63, wave = tid >> 6;
    const int quad = lane >> 4, lr = lane & 15;
    const size_t t0 = (size_t)blockIdx.x * 16;

    for (int i = tid; i < 16 * 256; i += 256) xs[i >> 8][i & 255] = x[t0 * DM + i];
    bvs[tid] = bv[tid]; g1s[tid] = g1[tid]; b1s[tid] = b1[tid];
    __syncthreads();

    {
        int tok = tid >> 4, l = tid & 15;
        float s = 0.f, s2 = 0.f;
        #pragma unroll
        for (int i = 0; i < 16; ++i) {
            float v = xs[tok][l + 16 * i];
            s += v; s2 += v * v;
        }
        #pragma unroll
        for (int m = 1; m < 16; m <<= 1) { s += __shfl_xor(s, m); s2 += __shfl_xor(s2, m); }
        if (l == 0) {
            float mean = s * (1.f / 256.f);
            float var  = s2 * (1.f / 256.f) - mean * mean;
            stat_m[tok] = mean;
            stat_r[tok] = rsqrtf(var + 1e-5f);
        }
    }
    __syncthreads();

    short8 av[8];
    {
        float mm = stat_m[lr], rr = stat_r[lr];
        #pragma unroll
        for (int kk = 0; kk < 8; ++kk) {
            #pragma unroll
            for (int j = 0; j < 8; ++j) {
                int k = kk * 32 + quad * 8 + j;
                float v = (xs[lr][k] - mm) * rr * g1s[k] + b1s[k];
                av[kk][j] = (short)f2bf(v);
            }
        }
    }
    floatx4 acc[4];
    #pragma unroll
    for (int nt = 0; nt < 4; ++nt) acc[nt] = (floatx4){0.f, 0.f, 0.f, 0.f};
    #pragma unroll
    for (int nt = 0; nt < 4; ++nt) {
        #pragma unroll
        for (int kk = 0; kk < 8; ++kk) {
            short8 bfr = *(const short8*)(Wvf + ((size_t)(((wave * 4 + nt) * 8 + kk) * 64) + lane) * 8);
            acc[nt] = __builtin_amdgcn_mfma_f32_16x16x32_bf16(av[kk], bfr, acc[nt], 0, 0, 0);
        }
    }
    #pragma unroll
    for (int nt = 0; nt < 4; ++nt) {
        int col = (wave * 4 + nt) * 16 + lr;
        float bb = bvs[col];
        #pragma unroll
        for (int reg = 0; reg < 4; ++reg) {
            int row = quad * 4 + reg;
            vall[(t0 + row) * DM + col] = acc[nt][reg] + bb;
        }
    }
}

// ---------------------------------------------------------------------------
// Kernel B: FUSED attn + ffn, 16 tokens/block. attn part = R8 verbatim.
// After the Wo epilogue, the block's 16 output rows stay in registers
// (oval[nt][reg]: same row/col mapping as ffn GEMM2 output) and the
// 16-token FFN runs in-block: LN -> GEMM1 -> GELU -> GEMM2 -> residual.
// Per-output-element accumulation chains identical to the standalone ffn
// (same kk order, same MFMA shape, same f2bf/gelu) -> bit-identical output.
// LDS: score buffer (32KB) overlaid by xs2+Af (24.8KB) then G (33KB);
// pool = 33024B -> still 4 blocks/CU. gf/bf/b1f/b2f read from global.
// ---------------------------------------------------------------------------
__global__ __launch_bounds__(256, 4) void attn_ffn_kernel(
    const float* __restrict__ x,
    const float* __restrict__ qn_g, const float* __restrict__ kn_g,
    const unsigned short* __restrict__ knTh, const unsigned short* __restrict__ knTl,
    const float* __restrict__ knsq_g,
    const float* __restrict__ vall,
    const unsigned short* __restrict__ Wof, const float* __restrict__ bo,
    const float* __restrict__ gf, const float* __restrict__ bf,
    const unsigned short* __restrict__ W1f, const float* __restrict__ b1f,
    const unsigned short* __restrict__ W2f, const float* __restrict__ b2f,
    const float* __restrict__ rw, float* __restrict__ out)
{
    __shared__ __align__(16) char pool[33024];
    __shared__ float stat_m[16], stat_r[16];
    float* s_ld   = (float*)pool;                       // 16x512 scores (32KB)
    float* attn_s = s_ld;                               // 16*128
    float* o8     = s_ld + 2048;                        // 16*260 (stride 260)
    float (*xs2)[260] = (float(*)[260])pool;            // 16640B (overlay)
    unsigned short* Af = (unsigned short*)(pool + 16640); // 8192B
    unsigned short (*G)[1032] = (unsigned short(*)[1032])pool; // 33024B (overlay)

    const int tid = threadIdx.x;
    const int lane = tid & 63, wave = tid >> 6;
    const int quad = lane >> 4, lr = lane & 15;
    const int sg = lane >> 5, sl = lane & 31;     // 32-lane subgroup
    const int sgid = wave * 2 + sg;               // 0..7
    const int b = blockIdx.x & 7;
    const int chunk = blockIdx.x >> 3;            // 0..127
    const size_t tq0 = (size_t)b * SEQ + (size_t)chunk * 16;
    const size_t rowb = (size_t)b * SEQ;

    half8 a_hi[4], a_lo[4];
    {
        const float* qrow = qn_g + (tq0 + lr) * DQK + quad * 8;
        #pragma unroll
        for (int kk = 0; kk < 4; ++kk) {
            float4 fa = *(const float4*)(qrow + kk * 32);
            float4 fb = *(const float4*)(qrow + kk * 32 + 4);
            float vv[8] = {fa.x, fa.y, fa.z, fa.w, fb.x, fb.y, fb.z, fb.w};
            #pragma unroll
            for (int j = 0; j < 8; ++j) {
                float v = vv[j];
                _Float16 h = (_Float16)v;
                a_hi[kk][j] = h;
                a_lo[kk][j] = (_Float16)((v - (float)h) * 4096.f);
            }
        }
    }

    const unsigned short* bh = knTh + (size_t)b * 262144;
    const unsigned short* bl = knTl + (size_t)b * 262144;
    const float* ksqb = knsq_g + rowb;

    ull c0[2], c1[2];          // candidate regs: lane sl holds ranks sl, sl+32

    for (int q4 = 0; q4 < 4; ++q4) {
        if (q4) __syncthreads();

        for (int t = 0; t < 8; ++t) {
            const int tile = q4 * 32 + wave * 8 + t;
            const unsigned short* ph = bh + (size_t)tile * 2048 + lane * 8;
            const unsigned short* pl = bl + (size_t)tile * 2048 + lane * 8;
            floatx4 am  = (floatx4){0.f, 0.f, 0.f, 0.f};
            floatx4 ax1 = (floatx4){0.f, 0.f, 0.f, 0.f};
            floatx4 ax2 = (floatx4){0.f, 0.f, 0.f, 0.f};
            #pragma unroll
            for (int kk = 0; kk < 4; ++kk) {
                half8 bhf = *(const half8*)(ph + kk * 512);
                half8 blf = *(const half8*)(pl + kk * 512);
                am  = __builtin_amdgcn_mfma_f32_16x16x32_f16(a_hi[kk], bhf, am,  0, 0, 0);
                ax1 = __builtin_amdgcn_mfma_f32_16x16x32_f16(a_hi[kk], blf, ax1, 0, 0, 0);
                ax2 = __builtin_amdgcn_mfma_f32_16x16x32_f16(a_lo[kk], bhf, ax2, 0, 0, 0);
            }
            const int keyloc = (wave * 8 + t) * 16 + lr;
            const float kq = ksqb[q4 * 512 + keyloc];
            #pragma unroll
            for (int r = 0; r < 4; ++r) {
                s_ld[(quad * 4 + r) * 512 + keyloc] =
                    2.f * (am[r] + (ax1[r] + ax2[r]) * (1.f / 4096.f)) - kq;
            }
        }
        __syncthreads();

        #pragma unroll
        for (int qi = 0; qi < 2; ++qi) {
            const int q = sgid + 8 * qi;
            const float* srow = &s_ld[q * 512 + sl];
            float f0 = -INFINITY, f1 = -INFINITY;
            int   i0 = 0, i1 = 0;
            #pragma unroll
            for (int i = 0; i < 16; ++i) {
                float f = srow[32 * i];
                int gidx = q4 * 512 + sl + 32 * i;
                bool a  = f > f0;
                bool bb = f > f1;
                f1 = a ? f0 : (bb ? f    : f1);
                i1 = a ? i0 : (bb ? gidx : i1);
                f0 = a ? f    : f0;
                i0 = a ? gidx : i0;
            }
            ull k2v = mkkey(f1, i1);
            ull cur = mkkey(f0, i0);
            int cnt = 0;
            for (int r = 0; r < NK; ++r) {
                ull w = cur;
                #pragma unroll
                for (int m = 1; m < 32; m <<= 1) {
                    ull o = shfl_xor_u64(w, m);
                    if (o > w) w = o;
                }
                const int slot = q4 * 16 + r;
                if (sl == slot)      c0[qi] = w;
                if (sl == slot - 32) c1[qi] = w;
                if (cur == w) {
                    ++cnt;
                    if (cnt == 1) cur = k2v;
                    else {
                        ull best = 0;
                        #pragma unroll
                        for (int i = 0; i < 16; ++i) {
                            float f = srow[32 * i];
                            ull k = mkkey(f, q4 * 512 + sl + 32 * i);
                            if (k < w && k > best) best = k;
                        }
                        cur = best;
                    }
                }
            }
        }
    }
    __syncthreads();

    int tidx[2] = {0, 0};
    #pragma unroll
    for (int qi = 0; qi < 2; ++qi) {
        ull ca = c0[qi], cb = c1[qi];
        ull hi = ca > cb ? ca : cb;
        ull lo = ca > cb ? cb : ca;
        ull cur = hi;
        int cnt = 0;
        for (int r = 0; r < NK; ++r) {
            ull w = cur;
            #pragma unroll
            for (int m = 1; m < 32; m <<= 1) {
                ull o = shfl_xor_u64(w, m);
                if (o > w) w = o;
            }
            if (sl == r) tidx[qi] = 2047 - (int)(unsigned int)(w & 0xFFFFFFFFull);
            if (cur == w) { ++cnt; cur = (cnt == 1) ? lo : 0ull; }
        }
    }

    #pragma unroll
    for (int qq = 0; qq < 4; ++qq) {
        const int sgq = qq & 1;
        const int qiq = qq >> 1;
        const int q   = wave * 2 + sgq + 8 * qiq;
        const int srcb = sgq * 32;
        const int h = lane >> 3;
        const int k1 = lane & 7, k2 = 8 + (lane & 7);
        const int i1 = __shfl(tidx[qiq], srcb + k1);
        const int i2 = __shfl(tidx[qiq], srcb + k2);
        const float* qrow = qn_g + (tq0 + q) * DQK + h * 16;
        const float* kr1 = kn_g + (rowb + i1) * DQK + h * 16;
        const float* kr2 = kn_g + (rowb + i2) * DQK + h * 16;
        float lg1 = 0.f, lg2 = 0.f;
        #pragma unroll
        for (int d = 0; d < 16; d += 4) {
            float4 qv = *(const float4*)&qrow[d];
            float4 a1 = *(const float4*)&kr1[d];
            float4 a2 = *(const float4*)&kr2[d];
            lg1 = fmaf(qv.x, a1.x, lg1); lg1 = fmaf(qv.y, a1.y, lg1);
            lg1 = fmaf(qv.z, a1.z, lg1); lg1 = fmaf(qv.w, a1.w, lg1);
            lg2 = fmaf(qv.x, a2.x, lg2); lg2 = fmaf(qv.y, a2.y, lg2);
            lg2 = fmaf(qv.z, a2.z, lg2); lg2 = fmaf(qv.w, a2.w, lg2);
        }
        lg1 *= 0.25f; lg2 *= 0.25f;
        float mx = fmaxf(lg1, lg2);
        #pragma unroll
        for (int m = 1; m < 8; m <<= 1) mx = fmaxf(mx, __shfl_xor(mx, m));
        float e1 = expf(lg1 - mx), e2 = expf(lg2 - mx);
        float ssum = e1 + e2;
        #pragma unroll
        for (int m = 1; m < 8; m <<= 1) ssum += __shfl_xor(ssum, m);
        attn_s[q * 128 + h * 16 + k1] = e1 / ssum;
        attn_s[q * 128 + h * 16 + k2] = e2 / ssum;
        // within-wave LDS RAW: ordered by lgkmcnt, no barrier needed

        float o[4] = {0.f, 0.f, 0.f, 0.f};
        for (int k = 0; k < NK; ++k) {
            const int ik = __shfl(tidx[qiq], srcb + k);
            const float* vr = vall + (rowb + ik) * DM;
            #pragma unroll
            for (int j = 0; j < 4; ++j) {
                int d = lane + 64 * j;
                o[j] = fmaf(attn_s[q * 128 + (d >> 5) * 16 + k], vr[d], o[j]);
            }
        }
        #pragma unroll
        for (int j = 0; j < 4; ++j) o8[q * 260 + lane + 64 * j] = o[j];
    }
    __syncthreads();    // o8 is read cross-wave in the Wo phase

    // ---- Wo via bf16 MFMA; outputs stay in registers (oval) ----
    float rwv = rw[0];
    float oval[4][4];
    {
        short8 ao[8];
        #pragma unroll
        for (int kk = 0; kk < 8; ++kk) {
            #pragma unroll
            for (int j = 0; j < 8; ++j) {
                int k = kk * 32 + quad * 8 + j;
                ao[kk][j] = (short)f2bf(o8[lr * 260 + k]);
            }
        }
        __syncthreads();    // all o8 reads done; xs2 may overlay pool below
        floatx4 aw[4];
        #pragma unroll
        for (int nt = 0; nt < 4; ++nt) aw[nt] = (floatx4){0.f, 0.f, 0.f, 0.f};
        #pragma unroll
        for (int nt = 0; nt < 4; ++nt) {
            #pragma unroll
            for (int kk = 0; kk < 8; ++kk) {
                short8 bofr = *(const short8*)(Wof + ((size_t)(((wave * 4 + nt) * 8 + kk) * 64) + lane) * 8);
                aw[nt] = __builtin_amdgcn_mfma_f32_16x16x32_bf16(ao[kk], bofr, aw[nt], 0, 0, 0);
            }
        }
        #pragma unroll
        for (int nt = 0; nt < 4; ++nt) {
            int col = (wave * 4 + nt) * 16 + lr;
            float bov = bo[col];
            #pragma unroll
            for (int reg = 0; reg < 4; ++reg) {
                int row = quad * 4 + reg;
                float v = x[(tq0 + row) * DM + col] + (aw[nt][reg] + bov) * rwv;
                oval[nt][reg] = v;
                xs2[row][col] = v;            // stage for LN / fragments
            }
        }
    }
    __syncthreads();    // xs2 complete (cross-wave reads follow)

    // ---- FFN phase (16 tokens) — math identical to standalone ffn ----
    {
        int tok = tid >> 4, l = tid & 15;
        float s = 0.f, s2 = 0.f;
        #pragma unroll
        for (int i = 0; i < 16; ++i) {
            float v = xs2[tok][l + 16 * i];
            s += v; s2 += v * v;
        }
        #pragma unroll
        for (int m = 1; m < 16; m <<= 1) { s += __shfl_xor(s, m); s2 += __shfl_xor(s2, m); }
        if (l == 0) {
            float mean = s * (1.f / 256.f);
            float var  = s2 * (1.f / 256.f) - mean * mean;
            stat_m[tok] = mean;
            stat_r[tok] = rsqrtf(var + 1e-5f);
        }
    }
    __syncthreads();

    // A-fragments (rows 0..15): wave handles kk = wave, wave+4
    for (int kk = wave; kk < 8; kk += 4) {
        int m = lr, k0 = kk * 32 + quad * 8;
        float mm = stat_m[m], rr = stat_r[m];
        unsigned int pk[4];
        #pragma unroll
        for (int jj = 0; jj < 4; ++jj) {
            int ka = k0 + 2 * jj, kb = ka + 1;
            float v0 = (xs2[m][ka] - mm) * rr * gf[ka] + bf[ka];
            float v1 = (xs2[m][kb] - mm) * rr * gf[kb] + bf[kb];
            pk[jj] = (unsigned int)f2bf(v0) | ((unsigned int)f2bf(v1) << 16);
        }
        *(uint4*)&Af[(kk * 64 + lane) * 8] = make_uint4(pk[0], pk[1], pk[2], pk[3]);
    }
    __syncthreads();

    short8 afr[8];
    #pragma unroll
    for (int kk = 0; kk < 8; ++kk)
        afr[kk] = *(const short8*)&Af[(kk * 64 + lane) * 8];
    __syncthreads();    // xs2/Af reads done before G overlays the pool

    // GEMM1: wave owns col-tiles ntg = wave*16+nt, nt=0..15
    for (int nt = 0; nt < 16; ++nt) {
        floatx4 acc = (floatx4){0.f, 0.f, 0.f, 0.f};
        const int ntg = wave * 16 + nt;
        #pragma unroll
        for (int kk = 0; kk < 8; ++kk) {
            short8 bfr = *(const short8*)(W1f + (size_t)((ntg * 8 + kk) * 64 + lane) * 8);
            acc = __builtin_amdgcn_mfma_f32_16x16x32_bf16(afr[kk], bfr, acc, 0, 0, 0);
        }
        const int n = ntg * 16 + lr;
        const float bb = b1f[n];
        #pragma unroll
        for (int reg = 0; reg < 4; ++reg) {
            int row = quad * 4 + reg;
            G[row][n] = f2bf(gelu_fast(acc[reg] + bb));
        }
    }
    __syncthreads();

    // GEMM2: wave owns col-tiles ct = wave*4+nt2, nt2=0..3
    floatx4 acc2[4];
    #pragma unroll
    for (int nt2 = 0; nt2 < 4; ++nt2) acc2[nt2] = (floatx4){0.f, 0.f, 0.f, 0.f};
    for (int kk2 = 0; kk2 < 32; ++kk2) {
        short8 a2 = *(const short8*)&G[lr][kk2 * 32 + quad * 8];
        #pragma unroll
        for (int nt2 = 0; nt2 < 4; ++nt2) {
            short8 b2 = *(const short8*)(W2f + (size_t)((((wave * 4 + nt2) * 32 + kk2) * 64 + lane) * 8));
            acc2[nt2] = __builtin_amdgcn_mfma_f32_16x16x32_bf16(a2, b2, acc2[nt2], 0, 0, 0);
        }
    }

    #pragma unroll
    for (int nt2 = 0; nt2 < 4; ++nt2) {
        int col = (wave * 4 + nt2) * 16 + lr;
        float bb = b2f[col];
        #pragma unroll
        for (int reg = 0; reg < 4; ++reg) {
            int row = quad * 4 + reg;
            float o = acc2[nt2][reg] + bb;
            out[(tq0 + row) * DM + col] = oval[nt2][reg] + o * rwv;
        }
    }
}

// ---------------------------------------------------------------------------
extern "C" void kernel_launch(void* const* d_in, const int* in_sizes, int n_in,
                              void* d_out, int out_size, void* d_ws, size_t ws_size,
                              hipStream_t stream)
{
    const float* x   = (const float*)d_in[0];
    const float* Wq  = (const float*)d_in[1];
    const float* bq  = (const float*)d_in[2];
    const float* Wk  = (const float*)d_in[3];
    const float* bk  = (const float*)d_in[4];
    const float* Wv  = (const float*)d_in[5];
    const float* bv  = (const float*)d_in[6];
    const float* Wo  = (const float*)d_in[7];
    const float* bo  = (const float*)d_in[8];
    const float* g1  = (const float*)d_in[9];
    const float* b1  = (const float*)d_in[10];
    const float* gf  = (const float*)d_in[11];
    const float* bf  = (const float*)d_in[12];
    const float* W1  = (const float*)d_in[13];
    const float* b1f = (const float*)d_in[14];
    const float* W2  = (const float*)d_in[15];
    const float* b2f = (const float*)d_in[16];
    const float* rw  = (const float*)d_in[17];
    float* out = (float*)d_out;

    // workspace (~43.3 MB): qn | kn | knTh/knTl | vall | knsq | W1f | W2f | Wvf | Wof
    float* ws   = (float*)d_ws;
    float* qn   = ws;                          // 2,097,152 floats
    float* kn   = ws + 2097152;                // 2,097,152
    unsigned short* knTh = (unsigned short*)(ws + 4194304);  // 2,097,152 shorts (4MB)
    unsigned short* knTl = knTh + 2097152;                   // 2,097,152 shorts (4MB)
    float* vall = ws + 6291456;                // 4,194,304
    float* knsq = ws + 10485760;               // 16,384
    unsigned short* W1f = (unsigned short*)(ws + 10502144);   // 262,144 shorts
    unsigned short* W2f = W1f + 262144;                       // 262,144
    unsigned short* Wvf = W2f + 262144;                       // 65,536
    unsigned short* Wof = Wvf + 65536;                        // 65,536

    conv_kernel<<<320, 256, 0, stream>>>(W1, W2, Wv, Wo, W1f, W2f, Wvf, Wof);
    proj_qk_kernel<<<BATCH * SEQ / 8, 256, 0, stream>>>(x, Wq, bq, Wk, bk,
                                                        qn, kn, knTh, knTl, knsq);
    proj_v_kernel<<<BATCH * SEQ / 16, 256, 0, stream>>>(x, bv, g1, b1, Wvf, vall);
    attn_ffn_kernel<<<BATCH * SEQ / 16, 256, 0, stream>>>(
        x, qn, kn, knTh, knTl, knsq, vall, Wof, bo,
        gf, bf, W1f, b1f, W2f, b2f, rw, out);
}

// Round 14
// 325.838 us; speedup vs baseline: 1.2823x; 1.0202x over previous
//
#include <hip/hip_runtime.h>
#include <math.h>

#define BATCH 8
#define SEQ   2048
#define DM    256
#define DQK   128
#define NHEADS 8
#define NK    16
#define DFF   1024

typedef __attribute__((ext_vector_type(8))) short short8;
typedef __attribute__((ext_vector_type(8))) _Float16 half8;
typedef __attribute__((ext_vector_type(4))) float floatx4;
typedef unsigned long long ull;

__device__ __forceinline__ unsigned short f2bf(float f) {
    unsigned int u = __float_as_uint(f);
    u += 0x7fffu + ((u >> 16) & 1u);          // round-to-nearest-even
    return (unsigned short)(u >> 16);
}

__device__ __forceinline__ float gelu_fast(float h) {
    float y = 0.7978845608028654f * (h + 0.044715f * h * h * h);
    float e = __expf(2.f * y);
    float t = 1.f - 2.f / (e + 1.f);
    return 0.5f * h * (1.f + t);
}

// composite sort key: primary score desc, secondary idx asc. Unique per idx.
__device__ __forceinline__ ull mkkey(float f, int gidx) {
    unsigned int u = __float_as_uint(f);
    u ^= (unsigned int)((int)u >> 31) | 0x80000000u;   // sortable float
    return ((ull)u << 32) | (unsigned int)(2047 - gidx);
}

__device__ __forceinline__ ull shfl_xor_u64(ull v, int m) {
    unsigned int lo = (unsigned int)v, hi = (unsigned int)(v >> 32);
    lo = __shfl_xor(lo, m);
    hi = __shfl_xor(hi, m);
    return ((ull)hi << 32) | lo;
}

// ---------------------------------------------------------------------------
// Kernel W: repack W1/W2/Wv/Wo fp32 -> bf16 MFMA B-fragment order (verbatim).
// ---------------------------------------------------------------------------
__global__ __launch_bounds__(256) void conv_kernel(
    const float* __restrict__ W1, const float* __restrict__ W2,
    const float* __restrict__ Wv, const float* __restrict__ Wo,
    unsigned short* __restrict__ W1f, unsigned short* __restrict__ W2f,
    unsigned short* __restrict__ Wvf, unsigned short* __restrict__ Wof)
{
    int g = blockIdx.x * 256 + threadIdx.x;
    const float* W; unsigned short* O; int e, stride;
    if (g < 32768)      { W = W1; O = W1f; e = g;         stride = DFF; }
    else if (g < 65536) { W = W2; O = W2f; e = g - 32768; stride = DM;  }
    else if (g < 73728) { W = Wv; O = Wvf; e = g - 65536; stride = DM;  }
    else                { W = Wo; O = Wof; e = g - 73728; stride = DM;  }
    int lane = e & 63;
    int kk, nt;
    if (g < 32768)      { kk = (e >> 6) & 7;  nt = e >> 9;  }
    else if (g < 65536) { kk = (e >> 6) & 31; nt = e >> 11; }
    else                { kk = (e >> 6) & 7;  nt = e >> 9;  }
    int n = nt * 16 + (lane & 15);
    int k0 = kk * 32 + (lane >> 4) * 8;
    unsigned int pk[4];
    #pragma unroll
    for (int jj = 0; jj < 4; ++jj) {
        unsigned short lo = f2bf(W[(size_t)(k0 + 2 * jj) * stride + n]);
        unsigned short hi = f2bf(W[(size_t)(k0 + 2 * jj + 1) * stride + n]);
        pk[jj] = (unsigned int)lo | ((unsigned int)hi << 16);
    }
    *(uint4*)(O + (size_t)e * 8) = make_uint4(pk[0], pk[1], pk[2], pk[3]);
}

// ---------------------------------------------------------------------------
// Kernel P: MERGED projections. Blocks 0..2047 run the proj_qk path
// (R8 verbatim); blocks 2048..3071 run the proj_v path (verbatim).
// The two are data-independent (both read x + own weights, disjoint
// outputs), so one dispatch lets the HW co-schedule VALU-bound qk blocks
// with MFMA-bound v blocks (m114: separate pipes overlap, time ~ max).
// Shared memory = union pool (19.9KB = max of the two) -> 8 blocks/CU.
// ---------------------------------------------------------------------------
__global__ __launch_bounds__(256) void proj_merged_kernel(
    const float* __restrict__ x,
    const float* __restrict__ Wq, const float* __restrict__ bq,
    const float* __restrict__ Wk, const float* __restrict__ bk,
    const float* __restrict__ bv, const float* __restrict__ g1,
    const float* __restrict__ b1,
    const unsigned short* __restrict__ Wvf,
    float* __restrict__ qn, float* __restrict__ kn,
    unsigned short* __restrict__ knTh, unsigned short* __restrict__ knTl,
    float* __restrict__ knsq, float* __restrict__ vall)
{
    __shared__ __align__(16) char pool[19840];
    const int tid = threadIdx.x;

    if (blockIdx.x < 2048) {
        // ================= proj_qk path (R8 verbatim) =================
        float* ks = (float*)pool;                          // 8*128 floats
        float (*nred)[2]  = (float(*)[2])(pool + 4096);    // [8][2]
        float (*kred)[2]  = (float(*)[2])(pool + 4160);
        float (*k2red)[2] = (float(*)[2])(pool + 4224);

        const int b = blockIdx.x & 7;
        const int chunk = blockIdx.x >> 3;
        const size_t t0 = (size_t)b * SEQ + (size_t)chunk * 8;

        {
            const int col = tid & 127, half = tid >> 7;
            const int half_u = __builtin_amdgcn_readfirstlane(half);
            const float* xrow[4];
            #pragma unroll
            for (int t = 0; t < 4; ++t)
                xrow[t] = x + (t0 + (size_t)(half_u * 4 + t)) * DM;

            float qa[4] = {0.f, 0.f, 0.f, 0.f}, ka[4] = {0.f, 0.f, 0.f, 0.f};
            for (int d = 0; d < 256; d += 4) {
                float4 xv[4];
                #pragma unroll
                for (int t = 0; t < 4; ++t) xv[t] = *(const float4*)(xrow[t] + d);
                #pragma unroll
                for (int dd = 0; dd < 4; ++dd) {
                    float wq = Wq[(d + dd) * DQK + col];
                    float wk = Wk[(d + dd) * DQK + col];
                    #pragma unroll
                    for (int t = 0; t < 4; ++t) {
                        float xval = (dd == 0) ? xv[t].x : (dd == 1) ? xv[t].y
                                   : (dd == 2) ? xv[t].z : xv[t].w;
                        qa[t] = fmaf(xval, wq, qa[t]);
                        ka[t] = fmaf(xval, wk, ka[t]);
                    }
                }
            }
            #pragma unroll
            for (int t = 0; t < 4; ++t) { qa[t] += bq[col]; ka[t] += bk[col]; }

            const int sub = (tid >> 6) & 1;
            #pragma unroll
            for (int t = 0; t < 4; ++t) {
                float sq = qa[t] * qa[t], sk = ka[t] * ka[t];
                #pragma unroll
                for (int m = 1; m < 64; m <<= 1) { sq += __shfl_xor(sq, m); sk += __shfl_xor(sk, m); }
                if ((tid & 63) == 0) { nred[half * 4 + t][sub] = sq; kred[half * 4 + t][sub] = sk; }
            }
            __syncthreads();
            float kvv[4];
            #pragma unroll
            for (int t = 0; t < 4; ++t) {
                int tok = half * 4 + t;
                float nq = sqrtf(nred[tok][0] + nred[tok][1]);
                float nk = sqrtf(kred[tok][0] + kred[tok][1]);
                float qv = qa[t] / fmaxf(nq, 1e-12f);
                float kv = ka[t] / fmaxf(nk, 1e-12f);
                qn[(t0 + tok) * DQK + col] = qv;
                kn[(t0 + tok) * DQK + col] = kv;
                ks[tok * 128 + col] = kv;
                kvv[t] = kv;
            }
            #pragma unroll
            for (int t = 0; t < 4; ++t) {
                float s2 = kvv[t] * kvv[t];
                #pragma unroll
                for (int m = 1; m < 64; m <<= 1) s2 += __shfl_xor(s2, m);
                if ((tid & 63) == 0) k2red[half * 4 + t][sub] = s2;
            }
            __syncthreads();
            if (tid < 8) knsq[t0 + tid] = k2red[tid][0] + k2red[tid][1];
        }

        // --- K^T -> fp16 hi/lo B-fragments ---
        {
            const int e   = tid & 127;
            const int sel = tid >> 7;           // 0 = hi, 1 = lo(*4096)
            const int key = e & 7;
            const int kq  = e >> 3;             // kk*4 + qd
            const int kk  = kq >> 2, qd = kq & 3;
            const int nt  = chunk >> 1;
            const int n   = ((chunk & 1) << 3) + key;
            const float* src = &ks[key * 128 + kk * 32 + qd * 8];
            unsigned int pk[4];
            #pragma unroll
            for (int jj = 0; jj < 4; ++jj) {
                float v0 = src[2 * jj], v1 = src[2 * jj + 1];
                _Float16 h0 = (_Float16)v0, h1 = (_Float16)v1;
                unsigned short u0, u1;
                if (sel == 0) {
                    u0 = __builtin_bit_cast(unsigned short, h0);
                    u1 = __builtin_bit_cast(unsigned short, h1);
                } else {
                    _Float16 l0 = (_Float16)((v0 - (float)h0) * 4096.f);
                    _Float16 l1 = (_Float16)((v1 - (float)h1) * 4096.f);
                    u0 = __builtin_bit_cast(unsigned short, l0);
                    u1 = __builtin_bit_cast(unsigned short, l1);
                }
                pk[jj] = (unsigned int)u0 | ((unsigned int)u1 << 16);
            }
            unsigned short* dst = (sel ? knTl : knTh)
                + (size_t)b * 262144
                + (size_t)((nt * 4 + kk) * 64 + qd * 16 + n) * 8;
            *(uint4*)dst = make_uint4(pk[0], pk[1], pk[2], pk[3]);
        }
    } else {
        // ================= proj_v path (verbatim) =================
        float (*xs)[260] = (float(*)[260])pool;            // 16640B
        float* stat_m = (float*)(pool + 16640);            // 64B
        float* stat_r = (float*)(pool + 16704);            // 64B
        float* bvs = (float*)(pool + 16768);               // 1024B
        float* g1s = (float*)(pool + 17792);               // 1024B
        float* b1s = (float*)(pool + 18816);               // 1024B

        const int lane = tid & 63, wave = tid >> 6;
        const int quad = lane >> 4, lr = lane & 15;
        const size_t t0 = (size_t)(blockIdx.x - 2048) * 16;

        for (int i = tid; i < 16 * 256; i += 256) xs[i >> 8][i & 255] = x[t0 * DM + i];
        bvs[tid] = bv[tid]; g1s[tid] = g1[tid]; b1s[tid] = b1[tid];
        __syncthreads();

        {
            int tok = tid >> 4, l = tid & 15;
            float s = 0.f, s2 = 0.f;
            #pragma unroll
            for (int i = 0; i < 16; ++i) {
                float v = xs[tok][l + 16 * i];
                s += v; s2 += v * v;
            }
            #pragma unroll
            for (int m = 1; m < 16; m <<= 1) { s += __shfl_xor(s, m); s2 += __shfl_xor(s2, m); }
            if (l == 0) {
                float mean = s * (1.f / 256.f);
                float var  = s2 * (1.f / 256.f) - mean * mean;
                stat_m[tok] = mean;
                stat_r[tok] = rsqrtf(var + 1e-5f);
            }
        }
        __syncthreads();

        short8 av[8];
        {
            float mm = stat_m[lr], rr = stat_r[lr];
            #pragma unroll
            for (int kk = 0; kk < 8; ++kk) {
                #pragma unroll
                for (int j = 0; j < 8; ++j) {
                    int k = kk * 32 + quad * 8 + j;
                    float v = (xs[lr][k] - mm) * rr * g1s[k] + b1s[k];
                    av[kk][j] = (short)f2bf(v);
                }
            }
        }
        floatx4 acc[4];
        #pragma unroll
        for (int nt = 0; nt < 4; ++nt) acc[nt] = (floatx4){0.f, 0.f, 0.f, 0.f};
        #pragma unroll
        for (int nt = 0; nt < 4; ++nt) {
            #pragma unroll
            for (int kk = 0; kk < 8; ++kk) {
                short8 bfr = *(const short8*)(Wvf + ((size_t)(((wave * 4 + nt) * 8 + kk) * 64) + lane) * 8);
                acc[nt] = __builtin_amdgcn_mfma_f32_16x16x32_bf16(av[kk], bfr, acc[nt], 0, 0, 0);
            }
        }
        #pragma unroll
        for (int nt = 0; nt < 4; ++nt) {
            int col = (wave * 4 + nt) * 16 + lr;
            float bb = bvs[col];
            #pragma unroll
            for (int reg = 0; reg < 4; ++reg) {
                int row = quad * 4 + reg;
                vall[(t0 + row) * DM + col] = acc[nt][reg] + bb;
            }
        }
    }
}

// ---------------------------------------------------------------------------
// Kernel B: FUSED attn + ffn, 16 tokens/block (R13 verbatim — passing, 203us).
// ---------------------------------------------------------------------------
__global__ __launch_bounds__(256, 4) void attn_ffn_kernel(
    const float* __restrict__ x,
    const float* __restrict__ qn_g, const float* __restrict__ kn_g,
    const unsigned short* __restrict__ knTh, const unsigned short* __restrict__ knTl,
    const float* __restrict__ knsq_g,
    const float* __restrict__ vall,
    const unsigned short* __restrict__ Wof, const float* __restrict__ bo,
    const float* __restrict__ gf, const float* __restrict__ bf,
    const unsigned short* __restrict__ W1f, const float* __restrict__ b1f,
    const unsigned short* __restrict__ W2f, const float* __restrict__ b2f,
    const float* __restrict__ rw, float* __restrict__ out)
{
    __shared__ __align__(16) char pool[33024];
    __shared__ float stat_m[16], stat_r[16];
    float* s_ld   = (float*)pool;                       // 16x512 scores (32KB)
    float* attn_s = s_ld;                               // 16*128
    float* o8     = s_ld + 2048;                        // 16*260 (stride 260)
    float (*xs2)[260] = (float(*)[260])pool;            // 16640B (overlay)
    unsigned short* Af = (unsigned short*)(pool + 16640); // 8192B
    unsigned short (*G)[1032] = (unsigned short(*)[1032])pool; // 33024B (overlay)

    const int tid = threadIdx.x;
    const int lane = tid & 63, wave = tid >> 6;
    const int quad = lane >> 4, lr = lane & 15;
    const int sg = lane >> 5, sl = lane & 31;     // 32-lane subgroup
    const int sgid = wave * 2 + sg;               // 0..7
    const int b = blockIdx.x & 7;
    const int chunk = blockIdx.x >> 3;            // 0..127
    const size_t tq0 = (size_t)b * SEQ + (size_t)chunk * 16;
    const size_t rowb = (size_t)b * SEQ;

    half8 a_hi[4], a_lo[4];
    {
        const float* qrow = qn_g + (tq0 + lr) * DQK + quad * 8;
        #pragma unroll
        for (int kk = 0; kk < 4; ++kk) {
            float4 fa = *(const float4*)(qrow + kk * 32);
            float4 fb = *(const float4*)(qrow + kk * 32 + 4);
            float vv[8] = {fa.x, fa.y, fa.z, fa.w, fb.x, fb.y, fb.z, fb.w};
            #pragma unroll
            for (int j = 0; j < 8; ++j) {
                float v = vv[j];
                _Float16 h = (_Float16)v;
                a_hi[kk][j] = h;
                a_lo[kk][j] = (_Float16)((v - (float)h) * 4096.f);
            }
        }
    }

    const unsigned short* bh = knTh + (size_t)b * 262144;
    const unsigned short* bl = knTl + (size_t)b * 262144;
    const float* ksqb = knsq_g + rowb;

    ull c0[2], c1[2];          // candidate regs: lane sl holds ranks sl, sl+32

    for (int q4 = 0; q4 < 4; ++q4) {
        if (q4) __syncthreads();

        for (int t = 0; t < 8; ++t) {
            const int tile = q4 * 32 + wave * 8 + t;
            const unsigned short* ph = bh + (size_t)tile * 2048 + lane * 8;
            const unsigned short* pl = bl + (size_t)tile * 2048 + lane * 8;
            floatx4 am  = (floatx4){0.f, 0.f, 0.f, 0.f};
            floatx4 ax1 = (floatx4){0.f, 0.f, 0.f, 0.f};
            floatx4 ax2 = (floatx4){0.f, 0.f, 0.f, 0.f};
            #pragma unroll
            for (int kk = 0; kk < 4; ++kk) {
                half8 bhf = *(const half8*)(ph + kk * 512);
                half8 blf = *(const half8*)(pl + kk * 512);
                am  = __builtin_amdgcn_mfma_f32_16x16x32_f16(a_hi[kk], bhf, am,  0, 0, 0);
                ax1 = __builtin_amdgcn_mfma_f32_16x16x32_f16(a_hi[kk], blf, ax1, 0, 0, 0);
                ax2 = __builtin_amdgcn_mfma_f32_16x16x32_f16(a_lo[kk], bhf, ax2, 0, 0, 0);
            }
            const int keyloc = (wave * 8 + t) * 16 + lr;
            const float kq = ksqb[q4 * 512 + keyloc];
            #pragma unroll
            for (int r = 0; r < 4; ++r) {
                s_ld[(quad * 4 + r) * 512 + keyloc] =
                    2.f * (am[r] + (ax1[r] + ax2[r]) * (1.f / 4096.f)) - kq;
            }
        }
        __syncthreads();

        #pragma unroll
        for (int qi = 0; qi < 2; ++qi) {
            const int q = sgid + 8 * qi;
            const float* srow = &s_ld[q * 512 + sl];
            float f0 = -INFINITY, f1 = -INFINITY;
            int   i0 = 0, i1 = 0;
            #pragma unroll
            for (int i = 0; i < 16; ++i) {
                float f = srow[32 * i];
                int gidx = q4 * 512 + sl + 32 * i;
                bool a  = f > f0;
                bool bb = f > f1;
                f1 = a ? f0 : (bb ? f    : f1);
                i1 = a ? i0 : (bb ? gidx : i1);
                f0 = a ? f    : f0;
                i0 = a ? gidx : i0;
            }
            ull k2v = mkkey(f1, i1);
            ull cur = mkkey(f0, i0);
            int cnt = 0;
            for (int r = 0; r < NK; ++r) {
                ull w = cur;
                #pragma unroll
                for (int m = 1; m < 32; m <<= 1) {
                    ull o = shfl_xor_u64(w, m);
                    if (o > w) w = o;
                }
                const int slot = q4 * 16 + r;
                if (sl == slot)      c0[qi] = w;
                if (sl == slot - 32) c1[qi] = w;
                if (cur == w) {
                    ++cnt;
                    if (cnt == 1) cur = k2v;
                    else {
                        ull best = 0;
                        #pragma unroll
                        for (int i = 0; i < 16; ++i) {
                            float f = srow[32 * i];
                            ull k = mkkey(f, q4 * 512 + sl + 32 * i);
                            if (k < w && k > best) best = k;
                        }
                        cur = best;
                    }
                }
            }
        }
    }
    __syncthreads();

    int tidx[2] = {0, 0};
    #pragma unroll
    for (int qi = 0; qi < 2; ++qi) {
        ull ca = c0[qi], cb = c1[qi];
        ull hi = ca > cb ? ca : cb;
        ull lo = ca > cb ? cb : ca;
        ull cur = hi;
        int cnt = 0;
        for (int r = 0; r < NK; ++r) {
            ull w = cur;
            #pragma unroll
            for (int m = 1; m < 32; m <<= 1) {
                ull o = shfl_xor_u64(w, m);
                if (o > w) w = o;
            }
            if (sl == r) tidx[qi] = 2047 - (int)(unsigned int)(w & 0xFFFFFFFFull);
            if (cur == w) { ++cnt; cur = (cnt == 1) ? lo : 0ull; }
        }
    }

    #pragma unroll
    for (int qq = 0; qq < 4; ++qq) {
        const int sgq = qq & 1;
        const int qiq = qq >> 1;
        const int q   = wave * 2 + sgq + 8 * qiq;
        const int srcb = sgq * 32;
        const int h = lane >> 3;
        const int k1 = lane & 7, k2 = 8 + (lane & 7);
        const int i1 = __shfl(tidx[qiq], srcb + k1);
        const int i2 = __shfl(tidx[qiq], srcb + k2);
        const float* qrow = qn_g + (tq0 + q) * DQK + h * 16;
        const float* kr1 = kn_g + (rowb + i1) * DQK + h * 16;
        const float* kr2 = kn_g + (rowb + i2) * DQK + h * 16;
        float lg1 = 0.f, lg2 = 0.f;
        #pragma unroll
        for (int d = 0; d < 16; d += 4) {
            float4 qv = *(const float4*)&qrow[d];
            float4 a1 = *(const float4*)&kr1[d];
            float4 a2 = *(const float4*)&kr2[d];
            lg1 = fmaf(qv.x, a1.x, lg1); lg1 = fmaf(qv.y, a1.y, lg1);
            lg1 = fmaf(qv.z, a1.z, lg1); lg1 = fmaf(qv.w, a1.w, lg1);
            lg2 = fmaf(qv.x, a2.x, lg2); lg2 = fmaf(qv.y, a2.y, lg2);
            lg2 = fmaf(qv.z, a2.z, lg2); lg2 = fmaf(qv.w, a2.w, lg2);
        }
        lg1 *= 0.25f; lg2 *= 0.25f;
        float mx = fmaxf(lg1, lg2);
        #pragma unroll
        for (int m = 1; m < 8; m <<= 1) mx = fmaxf(mx, __shfl_xor(mx, m));
        float e1 = expf(lg1 - mx), e2 = expf(lg2 - mx);
        float ssum = e1 + e2;
        #pragma unroll
        for (int m = 1; m < 8; m <<= 1) ssum += __shfl_xor(ssum, m);
        attn_s[q * 128 + h * 16 + k1] = e1 / ssum;
        attn_s[q * 128 + h * 16 + k2] = e2 / ssum;
        // within-wave LDS RAW: ordered by lgkmcnt, no barrier needed

        float o[4] = {0.f, 0.f, 0.f, 0.f};
        for (int k = 0; k < NK; ++k) {
            const int ik = __shfl(tidx[qiq], srcb + k);
            const float* vr = vall + (rowb + ik) * DM;
            #pragma unroll
            for (int j = 0; j < 4; ++j) {
                int d = lane + 64 * j;
                o[j] = fmaf(attn_s[q * 128 + (d >> 5) * 16 + k], vr[d], o[j]);
            }
        }
        #pragma unroll
        for (int j = 0; j < 4; ++j) o8[q * 260 + lane + 64 * j] = o[j];
    }
    __syncthreads();    // o8 is read cross-wave in the Wo phase

    // ---- Wo via bf16 MFMA; outputs stay in registers (oval) ----
    float rwv = rw[0];
    float oval[4][4];
    {
        short8 ao[8];
        #pragma unroll
        for (int kk = 0; kk < 8; ++kk) {
            #pragma unroll
            for (int j = 0; j < 8; ++j) {
                int k = kk * 32 + quad * 8 + j;
                ao[kk][j] = (short)f2bf(o8[lr * 260 + k]);
            }
        }
        __syncthreads();    // all o8 reads done; xs2 may overlay pool below
        floatx4 aw[4];
        #pragma unroll
        for (int nt = 0; nt < 4; ++nt) aw[nt] = (floatx4){0.f, 0.f, 0.f, 0.f};
        #pragma unroll
        for (int nt = 0; nt < 4; ++nt) {
            #pragma unroll
            for (int kk = 0; kk < 8; ++kk) {
                short8 bofr = *(const short8*)(Wof + ((size_t)(((wave * 4 + nt) * 8 + kk) * 64) + lane) * 8);
                aw[nt] = __builtin_amdgcn_mfma_f32_16x16x32_bf16(ao[kk], bofr, aw[nt], 0, 0, 0);
            }
        }
        #pragma unroll
        for (int nt = 0; nt < 4; ++nt) {
            int col = (wave * 4 + nt) * 16 + lr;
            float bov = bo[col];
            #pragma unroll
            for (int reg = 0; reg < 4; ++reg) {
                int row = quad * 4 + reg;
                float v = x[(tq0 + row) * DM + col] + (aw[nt][reg] + bov) * rwv;
                oval[nt][reg] = v;
                xs2[row][col] = v;            // stage for LN / fragments
            }
        }
    }
    __syncthreads();    // xs2 complete (cross-wave reads follow)

    // ---- FFN phase (16 tokens) — math identical to standalone ffn ----
    {
        int tok = tid >> 4, l = tid & 15;
        float s = 0.f, s2 = 0.f;
        #pragma unroll
        for (int i = 0; i < 16; ++i) {
            float v = xs2[tok][l + 16 * i];
            s += v; s2 += v * v;
        }
        #pragma unroll
        for (int m = 1; m < 16; m <<= 1) { s += __shfl_xor(s, m); s2 += __shfl_xor(s2, m); }
        if (l == 0) {
            float mean = s * (1.f / 256.f);
            float var  = s2 * (1.f / 256.f) - mean * mean;
            stat_m[tok] = mean;
            stat_r[tok] = rsqrtf(var + 1e-5f);
        }
    }
    __syncthreads();

    // A-fragments (rows 0..15): wave handles kk = wave, wave+4
    for (int kk = wave; kk < 8; kk += 4) {
        int m = lr, k0 = kk * 32 + quad * 8;
        float mm = stat_m[m], rr = stat_r[m];
        unsigned int pk[4];
        #pragma unroll
        for (int jj = 0; jj < 4; ++jj) {
            int ka = k0 + 2 * jj, kb = ka + 1;
            float v0 = (xs2[m][ka] - mm) * rr * gf[ka] + bf[ka];
            float v1 = (xs2[m][kb] - mm) * rr * gf[kb] + bf[kb];
            pk[jj] = (unsigned int)f2bf(v0) | ((unsigned int)f2bf(v1) << 16);
        }
        *(uint4*)&Af[(kk * 64 + lane) * 8] = make_uint4(pk[0], pk[1], pk[2], pk[3]);
    }
    __syncthreads();

    short8 afr[8];
    #pragma unroll
    for (int kk = 0; kk < 8; ++kk)
        afr[kk] = *(const short8*)&Af[(kk * 64 + lane) * 8];
    __syncthreads();    // xs2/Af reads done before G overlays the pool

    // GEMM1: wave owns col-tiles ntg = wave*16+nt, nt=0..15
    for (int nt = 0; nt < 16; ++nt) {
        floatx4 acc = (floatx4){0.f, 0.f, 0.f, 0.f};
        const int ntg = wave * 16 + nt;
        #pragma unroll
        for (int kk = 0; kk < 8; ++kk) {
            short8 bfr = *(const short8*)(W1f + (size_t)((ntg * 8 + kk) * 64 + lane) * 8);
            acc = __builtin_amdgcn_mfma_f32_16x16x32_bf16(afr[kk], bfr, acc, 0, 0, 0);
        }
        const int n = ntg * 16 + lr;
        const float bb = b1f[n];
        #pragma unroll
        for (int reg = 0; reg < 4; ++reg) {
            int row = quad * 4 + reg;
            G[row][n] = f2bf(gelu_fast(acc[reg] + bb));
        }
    }
    __syncthreads();

    // GEMM2: wave owns col-tiles ct = wave*4+nt2, nt2=0..3
    floatx4 acc2[4];
    #pragma unroll
    for (int nt2 = 0; nt2 < 4; ++nt2) acc2[nt2] = (floatx4){0.f, 0.f, 0.f, 0.f};
    for (int kk2 = 0; kk2 < 32; ++kk2) {
        short8 a2 = *(const short8*)&G[lr][kk2 * 32 + quad * 8];
        #pragma unroll
        for (int nt2 = 0; nt2 < 4; ++nt2) {
            short8 b2 = *(const short8*)(W2f + (size_t)((((wave * 4 + nt2) * 32 + kk2) * 64 + lane) * 8));
            acc2[nt2] = __builtin_amdgcn_mfma_f32_16x16x32_bf16(a2, b2, acc2[nt2], 0, 0, 0);
        }
    }

    #pragma unroll
    for (int nt2 = 0; nt2 < 4; ++nt2) {
        int col = (wave * 4 + nt2) * 16 + lr;
        float bb = b2f[col];
        #pragma unroll
        for (int reg = 0; reg < 4; ++reg) {
            int row = quad * 4 + reg;
            float o = acc2[nt2][reg] + bb;
            out[(tq0 + row) * DM + col] = oval[nt2][reg] + o * rwv;
        }
    }
}

// ---------------------------------------------------------------------------
extern "C" void kernel_launch(void* const* d_in, const int* in_sizes, int n_in,
                              void* d_out, int out_size, void* d_ws, size_t ws_size,
                              hipStream_t stream)
{
    const float* x   = (const float*)d_in[0];
    const float* Wq  = (const float*)d_in[1];
    const float* bq  = (const float*)d_in[2];
    const float* Wk  = (const float*)d_in[3];
    const float* bk  = (const float*)d_in[4];
    const float* Wv  = (const float*)d_in[5];
    const float* bv  = (const float*)d_in[6];
    const float* Wo  = (const float*)d_in[7];
    const float* bo  = (const float*)d_in[8];
    const float* g1  = (const float*)d_in[9];
    const float* b1  = (const float*)d_in[10];
    const float* gf  = (const float*)d_in[11];
    const float* bf  = (const float*)d_in[12];
    const float* W1  = (const float*)d_in[13];
    const float* b1f = (const float*)d_in[14];
    const float* W2  = (const float*)d_in[15];
    const float* b2f = (const float*)d_in[16];
    const float* rw  = (const float*)d_in[17];
    float* out = (float*)d_out;

    // workspace (~43.3 MB): qn | kn | knTh/knTl | vall | knsq | W1f | W2f | Wvf | Wof
    float* ws   = (float*)d_ws;
    float* qn   = ws;                          // 2,097,152 floats
    float* kn   = ws + 2097152;                // 2,097,152
    unsigned short* knTh = (unsigned short*)(ws + 4194304);  // 2,097,152 shorts (4MB)
    unsigned short* knTl = knTh + 2097152;                   // 2,097,152 shorts (4MB)
    float* vall = ws + 6291456;                // 4,194,304
    float* knsq = ws + 10485760;               // 16,384
    unsigned short* W1f = (unsigned short*)(ws + 10502144);   // 262,144 shorts
    unsigned short* W2f = W1f + 262144;                       // 262,144
    unsigned short* Wvf = W2f + 262144;                       // 65,536
    unsigned short* Wof = Wvf + 65536;                        // 65,536

    conv_kernel<<<320, 256, 0, stream>>>(W1, W2, Wv, Wo, W1f, W2f, Wvf, Wof);
    proj_merged_kernel<<<2048 + BATCH * SEQ / 16, 256, 0, stream>>>(
        x, Wq, bq, Wk, bk, bv, g1, b1, Wvf,
        qn, kn, knTh, knTl, knsq, vall);
    attn_ffn_kernel<<<BATCH * SEQ / 16, 256, 0, stream>>>(
        x, qn, kn, knTh, knTl, knsq, vall, Wof, bo,
        gf, bf, W1f, b1f, W2f, b2f, rw, out);
}